// Round 21
// baseline (911.113 us; speedup 1.0000x reference)
//
#include <hip/hip_runtime.h>
#include <math.h>

// ===== problem constants =====
#define NB   4
#define NS   1024
#define ND   1024
#define NH   16
#define NTOK 4096
#define NFE  1024
#define ETOK_CAP 10240

// (1/sqrt(96)) * log2(e) — applied to q at attention prologue load; scores in log2 domain
#define SCL_LOG2E 0.14724445f

// ===== workspace layout (f32 slot offsets) =====
static constexpr size_t OFF_GWP  = 0;          // 8,192
static constexpr size_t OFF_TKW  = 8192;       // 8,192
static constexpr size_t OFF_EW   = 16384;      // 10,240 (ends 26,624)
static constexpr size_t OFF_INT  = 26624;      // 18,496 ints = 18,496 slots (ends 45,120)
static constexpr size_t OFF_X    = 45184;      // 2,097,152: x_bf -> oproj -> ybuf (ends 2,142,336)
static constexpr size_t OFF_QA   = 2142336;    // qa f32 2M -> qbuf f32 6,291,456 (ends 8,433,792)
static constexpr size_t OFF_GATE = 2142336;    // gate_bf 4,194,304 (after attn); later down_bf
static constexpr size_t OFF_UP   = 6336640;    // up_bf 4,194,304 (after attn; ends 10,530,944)
static constexpr size_t OFF_QAB  = 8433792;    // qab bf16 1,048,576
static constexpr size_t OFF_KVP  = 9482368;    // kvp f32 1,179,648 (ends 10,662,016)
static constexpr size_t OFF_KVC  = 10662016;   // kvc bf16 589,824 (ends 11,251,840)
static constexpr size_t OFF_WA   = 11251840;   // weight pool 1,327,104 (dead after wo-gemm)
static constexpr size_t WA_WQA   = 0;
static constexpr size_t WA_WQB   = 262144;
static constexpr size_t WA_WKVA  = 655360;
static constexpr size_t WA_WO    = 802816;
static constexpr size_t OFF_ACT  = 10530944;   // actb bf16 5,242,880 (ends 15,773,824)
static constexpr size_t WS_FLOATS = 15773824;

typedef __attribute__((ext_vector_type(8))) short bf16x8_t;
typedef __attribute__((ext_vector_type(4))) float f32x4_t;

__device__ __forceinline__ unsigned pack2(float a, float b) {
  union { float f; unsigned u; } x, y; x.f = a; y.f = b;
  unsigned lo = (x.u + 0x7fffu + ((x.u >> 16) & 1u)) >> 16;
  unsigned hi = (y.u + 0x7fffu + ((y.u >> 16) & 1u)) & 0xffff0000u;
  return (lo & 0xffffu) | hi;
}
__device__ __forceinline__ unsigned short f2bfs(float f) {
  union { float f; unsigned u; } x; x.f = f;
  return (unsigned short)((x.u + 0x7fffu + ((x.u >> 16) & 1u)) >> 16);
}

// ===================== f32 -> bf16 conversion =====================
__global__ __launch_bounds__(256) void conv_bf16_kernel(
    const float* __restrict__ src, unsigned short* __restrict__ dst, int n)
{
  int i = (blockIdx.x * 256 + threadIdx.x) * 8;
  if (i >= n) return;
  float4 a = *(const float4*)(src + i);
  float4 b = *(const float4*)(src + i + 4);
  uint4 o;
  o.x = pack2(a.x, a.y); o.y = pack2(a.z, a.w);
  o.z = pack2(b.x, b.y); o.w = pack2(b.z, b.w);
  *(uint4*)(dst + i) = o;
}

// gwp[e][d] = gate_w[e][d] * post_ln_w[d]
__global__ __launch_bounds__(256) void conv_gwp_kernel(
    const float* __restrict__ gw, const float* __restrict__ pw, float* __restrict__ gwp)
{
  int i = blockIdx.x * 256 + threadIdx.x;
  gwp[i] = gw[i] * pw[i & 1023];
}

// ===================== RMSNorm (f32 in -> bf16 out) =====================
template<int PER>
__global__ __launch_bounds__(256) void rmsnorm_bf16(
    const float* in, int istr, const float* w, unsigned short* out, int ostr)
{
  int row = blockIdx.x, t = threadIdx.x;
  const float* ip = in + (size_t)row * istr;
  float v[PER];
  float ss = 0.f;
#pragma unroll
  for (int i = 0; i < PER; i++) { v[i] = ip[t + i*256]; ss += v[i]*v[i]; }
#pragma unroll
  for (int k = 1; k < 64; k <<= 1) ss += __shfl_xor(ss, k);
  __shared__ float red[4];
  if ((t & 63) == 0) red[t >> 6] = ss;
  __syncthreads();
  float tot = red[0] + red[1] + red[2] + red[3];
  float inv = rsqrtf(tot * (1.f / (PER * 256)) + 1e-6f);
  unsigned short* op = out + (size_t)row * ostr;
#pragma unroll
  for (int i = 0; i < PER; i++) op[t + i*256] = f2bfs(v[i] * inv * w[t + i*256]);
}

// ===================== fused post-LN rmsnorm + gate logits =====================
__global__ __launch_bounds__(256) void rms_gate_kernel(
    const float* __restrict__ H, const float* __restrict__ pw,
    const float* __restrict__ gwp, const float* __restrict__ gb,
    unsigned short* __restrict__ ybuf, float* __restrict__ logits)
{
  __shared__ __align__(16) float ly[1024];
  __shared__ float red[4];
  int tok = blockIdx.x, t = threadIdx.x;
  float4 hv = *(const float4*)(H + (size_t)tok * ND + t * 4);
  *(float4*)&ly[t * 4] = hv;
  float ss = hv.x*hv.x + hv.y*hv.y + hv.z*hv.z + hv.w*hv.w;
#pragma unroll
  for (int k = 1; k < 64; k <<= 1) ss += __shfl_xor(ss, k);
  if ((t & 63) == 0) red[t >> 6] = ss;
  __syncthreads();
  float inv = rsqrtf((red[0] + red[1] + red[2] + red[3]) * (1.f / 1024.f) + 1e-6f);
  float4 pw4 = *(const float4*)(pw + t * 4);
  unsigned short* yb = ybuf + (size_t)tok * ND + t * 4;
  yb[0] = f2bfs((hv.x * inv) * pw4.x);
  yb[1] = f2bfs((hv.y * inv) * pw4.y);
  yb[2] = f2bfs((hv.z * inv) * pw4.z);
  yb[3] = f2bfs((hv.w * inv) * pw4.w);
  int e = t >> 5, lane = t & 31;
  const float* w = gwp + (size_t)e * ND;
  float acc = 0.f;
  for (int d = lane; d < ND; d += 32) acc += ly[d] * w[d];
#pragma unroll
  for (int k = 16; k >= 1; k >>= 1) acc += __shfl_xor(acc, k);
  if (lane == 0) logits[(size_t)tok * 8 + e] = acc * inv + gb[e];
}

// ===================== bf16 MFMA GEMM: C = A @ W^T + bias (+resid) =====================
#define GSTR 72

template<bool OUTBF, bool RESID>
__global__ __launch_bounds__(256) void gemm_bf16(
    const unsigned short* __restrict__ A, int lda,
    const unsigned short* __restrict__ W, int ldw,
    const float* __restrict__ bias,
    const float* __restrict__ resid,
    void* __restrict__ Cv, int ldc, int N, int K)
{
  __shared__ __align__(16) unsigned short As[128 * GSTR];
  __shared__ __align__(16) unsigned short Ws2[128 * GSTR];
  int t = threadIdx.x;
  int m0 = blockIdx.y * 128, n0 = blockIdx.x * 128;
  int lane = t & 63, w = t >> 6;
  int mw = (w >> 1) * 64, nw = (w & 1) * 64;
  int lr = lane & 15, lg = lane >> 4;

  int srowv[4], sc8v[4];
#pragma unroll
  for (int it = 0; it < 4; it++) { int c = it*256 + t; srowv[it] = c >> 3; sc8v[it] = (c & 7) * 8; }

  uint4 pa[4], pw[4];
  auto ld = [&](int k0) {
#pragma unroll
    for (int it = 0; it < 4; it++) {
      pa[it] = *(const uint4*)(A + (size_t)(m0 + srowv[it]) * lda + k0 + sc8v[it]);
      int r = n0 + srowv[it];
      pw[it] = (r < N) ? *(const uint4*)(W + (size_t)r * ldw + k0 + sc8v[it])
                       : make_uint4(0u, 0u, 0u, 0u);
    }
  };
  auto st = [&]() {
#pragma unroll
    for (int it = 0; it < 4; it++) {
      *(uint4*)&As[srowv[it] * GSTR + sc8v[it]] = pa[it];
      *(uint4*)&Ws2[srowv[it] * GSTR + sc8v[it]] = pw[it];
    }
  };

  f32x4_t acc[4][4];
#pragma unroll
  for (int i = 0; i < 4; i++)
#pragma unroll
    for (int j = 0; j < 4; j++) acc[i][j] = (f32x4_t){0.f, 0.f, 0.f, 0.f};

  ld(0); st();
  __syncthreads();
  for (int k0 = 0; ; ) {
    int kn = k0 + 64;
    if (kn < K) ld(kn);
#pragma unroll
    for (int kk = 0; kk < 2; kk++) {
      bf16x8_t af[4], wf[4];
#pragma unroll
      for (int i = 0; i < 4; i++)
        af[i] = *(const bf16x8_t*)&As[(mw + 16*i + lr) * GSTR + kk*32 + lg*8];
#pragma unroll
      for (int j = 0; j < 4; j++)
        wf[j] = *(const bf16x8_t*)&Ws2[(nw + 16*j + lr) * GSTR + kk*32 + lg*8];
#pragma unroll
      for (int i = 0; i < 4; i++)
#pragma unroll
        for (int j = 0; j < 4; j++)
          acc[i][j] = __builtin_amdgcn_mfma_f32_16x16x32_bf16(af[i], wf[j], acc[i][j], 0, 0, 0);
    }
    k0 = kn;
    if (k0 >= K) break;
    __syncthreads();
    st();
    __syncthreads();
  }
#pragma unroll
  for (int j = 0; j < 4; j++) {
    int n = n0 + nw + 16*j + lr;
    if (n < N) {
      float bv = bias[n];
#pragma unroll
      for (int i = 0; i < 4; i++) {
#pragma unroll
        for (int r = 0; r < 4; r++) {
          int m = m0 + mw + 16*i + 4*lg + r;
          size_t off = (size_t)m * ldc + n;
          float v = acc[i][j][r] + bv;
          if (RESID) v += resid[off];
          if (OUTBF) ((unsigned short*)Cv)[off] = f2bfs(v);
          else       ((float*)Cv)[off] = v;
        }
      }
    }
  }
}

// ===================== RoPE (f32 qbuf) =====================
__global__ __launch_bounds__(256) void rope_q_kernel(float* qbuf)
{
  int id = blockIdx.x * 256 + threadIdx.x;     // NTOK*NH*16
  int d = id & 15;
  int h = (id >> 4) & 15;
  int sr = id >> 8;
  int s = sr & (NS - 1);
  float inv = __expf(-(float)(2 * d) * (9.210340371976184f / 32.f));
  float fr = (float)s * inv;
  float sn, cs; sincosf(fr, &sn, &cs);
  float* p = qbuf + (size_t)sr * 1536 + h * 96 + 64;
  float x1 = p[d], x2 = p[d + 16];
  p[d]      = x1 * cs - x2 * sn;
  p[d + 16] = x2 * cs + x1 * sn;
}

__global__ __launch_bounds__(256) void rope_k_kernel(const float* kvp, unsigned short* kvc)
{
  int id = blockIdx.x * 256 + threadIdx.x;     // NTOK*16
  int d = id & 15;
  int sr = id >> 4;
  int s = sr & (NS - 1);
  float inv = __expf(-(float)(2 * d) * (9.210340371976184f / 32.f));
  float fr = (float)s * inv;
  float sn, cs; sincosf(fr, &sn, &cs);
  const float* src = kvp + (size_t)sr * 288 + 256;
  unsigned short* dst = kvc + (size_t)sr * 288 + 256;
  float x1 = src[d], x2 = src[d + 16];
  dst[d]      = f2bfs(x1 * cs - x2 * sn);
  dst[d + 16] = f2bfs(x2 * cs + x1 * sn);
}

// ===================== MLA flash attention v13: dbuf ks/vt + shfl-P, 1 barrier/tile =====
// Arithmetic bit-identical to R17/R20: same score chains, mask, softmax, PV order; the
// P bf16 granules reach identical MFMA lane positions via __shfl instead of LDS ps.
// LDS: ks0/ks1 [32][296] @0/@9472 sh | vt0/vt1 [256][40] @18944/@29184 sh = 78,848 B.
#define KSTR 296
#define QNSTR 65
#define VPAD 40
#define OSTR2 132

__global__ __launch_bounds__(256, 2) void attn_kernel(
    const float* __restrict__ qbuf,           // (NTOK,1536) f32 post-rope
    const unsigned short* __restrict__ kvc,   // (NTOK,288) bf16
    const float* __restrict__ wkvb,           // (H*128,256) f32
    unsigned short* __restrict__ oproj)       // (NTOK,1024) bf16
{
  extern __shared__ float4 smem_f4[];
  unsigned short* sm  = (unsigned short*)smem_f4;
  unsigned short* ks  = sm;              // 2 x [32][KSTR]
  unsigned short* vt  = sm + 18944;      // 2 x [256][VPAD]
  float* qn           = (float*)sm;      // [64][QNSTR] prologue
  unsigned short* qst = sm + 8320;       // [64][KSTR] prologue
  float* o_lds        = (float*)sm;      // [64][OSTR2] epilogue

  int bx = blockIdx.x;                   // 0..7
  int h = blockIdx.y, b = blockIdx.z;
  int t = threadIdx.x;
  int lane = t & 63, wv_ = t >> 6;
  int lrow = lane & 15, lg = lane >> 4;
  int qrow = 16 * wv_ + lrow;

  // shfl sources for P-redistribution (lane needs keys 8lg..8lg+7 of its qrow)
  int sA = lrow + 16 * ((2 * lg) & 3);
  int sB = sA + 16;

  int srow[5], sc16[5];
#pragma unroll
  for (int it = 0; it < 5; it++) {
    int c = it * 256 + t;
    srow[it] = c / 36; sc16[it] = c % 36;
  }
  bool tail = (t < 128);

  for (int half = 0; half < 2; half++) {
    int qb = half ? bx : (15 - bx);      // heavy tile first
    int row0 = b * NS + qb * 64;
    __syncthreads();                     // previous half's LDS fully consumed

    // ---- prologue a: q_nope (f32, scaled) -> qn ; q_pe -> bq[8]
    for (int idx = t; idx < 4096; idx += 256) {
      int r = idx >> 6, c = idx & 63;
      qn[r * QNSTR + c] = qbuf[(size_t)(row0 + r) * 1536 + h * 96 + c] * SCL_LOG2E;
    }
    bf16x8_t bq[9];
    {
      const float* src = qbuf + (size_t)(row0 + qrow) * 1536 + h * 96 + 64 + lg * 8;
      unsigned short* bp = (unsigned short*)&bq[8];
#pragma unroll
      for (int j = 0; j < 8; j++) bp[j] = f2bfs(src[j] * SCL_LOG2E);
    }
    __syncthreads();
    // ---- prologue b: q_abs = q_nope @ wkv_b[h,0:64,:]  (f32 VALU, exact)
    {
      int cx = t & 63, ry = t >> 6;
      float a[16][4] = {};
      const float* wb = wkvb + (size_t)h * 32768 + cx * 4;
      for (int k = 0; k < 64; k++) {
        float4 wv = *(const float4*)(wb + (size_t)k * 256);
#pragma unroll
        for (int r = 0; r < 16; r++) {
          float qv = qn[(ry * 16 + r) * QNSTR + k];
          a[r][0] += qv * wv.x; a[r][1] += qv * wv.y; a[r][2] += qv * wv.z; a[r][3] += qv * wv.w;
        }
      }
      __syncthreads();   // qn reads done before qst (overlapping region) is written
#pragma unroll
      for (int r = 0; r < 16; r++) {
        uint2 pk; pk.x = pack2(a[r][0], a[r][1]); pk.y = pack2(a[r][2], a[r][3]);
        *(uint2*)&qst[(ry * 16 + r) * KSTR + cx * 4] = pk;
      }
    }
    __syncthreads();
#pragma unroll
    for (int kk = 0; kk < 8; kk++)
      bq[kk] = *(const bf16x8_t*)&qst[qrow * KSTR + kk * 32 + lg * 8];
    __syncthreads();

    // ---- loop state
    float m_run = -1e30f, l_run = 0.f;
    f32x4_t acco[16];
#pragma unroll
    for (int n = 0; n < 16; n++) acco[n] = (f32x4_t){0.f, 0.f, 0.f, 0.f};

    uint4 pa[5];
    unsigned short vg[32];

    auto issue = [&](int kb2) {
      const unsigned short* tb = kvc + ((size_t)b * NS + kb2 * 32) * 288;
#pragma unroll
      for (int it = 0; it < 4; it++)
        pa[it] = *(const uint4*)(tb + srow[it] * 288 + sc16[it] * 8);
      if (tail) pa[4] = *(const uint4*)(tb + srow[4] * 288 + sc16[4] * 8);
      const unsigned short* vsrc = tb + t;   // feature t, keys 0..31
#pragma unroll
      for (int k = 0; k < 32; k++) vg[k] = vsrc[k * 288];
    };
    auto commit = [&](int par) {
      unsigned short* ksb = ks + par * 9472;
      unsigned short* vtb = vt + par * 10240;
#pragma unroll
      for (int it = 0; it < 5; it++) {
        if (it == 4 && !tail) continue;
        *(uint4*)&ksb[srow[it] * KSTR + sc16[it] * 8] = pa[it];
      }
      unsigned wds[16];
#pragma unroll
      for (int j = 0; j < 16; j++)
        wds[j] = (unsigned)vg[2*j] | ((unsigned)vg[2*j+1] << 16);
#pragma unroll
      for (int j = 0; j < 4; j++)
        *(uint4*)&vtb[t * VPAD + j * 8] =
          make_uint4(wds[4*j], wds[4*j+1], wds[4*j+2], wds[4*j+3]);
    };

    int nkb = 2 * qb + 2;
    issue(0); commit(0);
    issue(1);
    __syncthreads();
    for (int kb = 0; kb < nkb; kb++) {
      int cur = kb & 1;
      if (kb + 1 < nkb) {
        commit(cur ^ 1);                 // flush regs of tile kb+1 into opposite buffer
        if (kb + 2 < nkb) issue(kb + 2); // loads covered by compute below
      }
      const unsigned short* ksb = ks + cur * 9472;
      const unsigned short* vtb = vt + cur * 10240;
      int key0 = kb * 32;
      // ---- scores (even/odd chains), K-dim 288
      f32x4_t s0e = {0.f,0.f,0.f,0.f}, s0o = {0.f,0.f,0.f,0.f};
      f32x4_t s1e = {0.f,0.f,0.f,0.f}, s1o = {0.f,0.f,0.f,0.f};
#pragma unroll
      for (int kk = 0; kk < 9; kk++) {
        bf16x8_t a0 = *(const bf16x8_t*)&ksb[lrow * KSTR + kk*32 + lg*8];
        bf16x8_t a1 = *(const bf16x8_t*)&ksb[(16 + lrow) * KSTR + kk*32 + lg*8];
        if (kk & 1) {
          s0o = __builtin_amdgcn_mfma_f32_16x16x32_bf16(a0, bq[kk], s0o, 0, 0, 0);
          s1o = __builtin_amdgcn_mfma_f32_16x16x32_bf16(a1, bq[kk], s1o, 0, 0, 0);
        } else {
          s0e = __builtin_amdgcn_mfma_f32_16x16x32_bf16(a0, bq[kk], s0e, 0, 0, 0);
          s1e = __builtin_amdgcn_mfma_f32_16x16x32_bf16(a1, bq[kk], s1e, 0, 0, 0);
        }
      }
      f32x4_t s0a = s0e + s0o, s1a = s1e + s1o;
      // ---- causal mask (skipped on full tiles) + online softmax in log2 domain
      int qg = qb * 64 + qrow;
      float sv[8];
      if (key0 + 31 > qb * 64 + 16 * wv_) {
#pragma unroll
        for (int r = 0; r < 4; r++) {
          sv[r]     = (key0 + 4*lg + r      <= qg) ? s0a[r] : -1e30f;
          sv[4 + r] = (key0 + 16 + 4*lg + r <= qg) ? s1a[r] : -1e30f;
        }
      } else {
#pragma unroll
        for (int r = 0; r < 4; r++) { sv[r] = s0a[r]; sv[4 + r] = s1a[r]; }
      }
      float mx = sv[0];
#pragma unroll
      for (int i = 1; i < 8; i++) mx = fmaxf(mx, sv[i]);
      mx = fmaxf(mx, __shfl_xor(mx, 16));
      mx = fmaxf(mx, __shfl_xor(mx, 32));
      if (!__all(mx - m_run <= 11.0f)) {   // defer-max (T13)
        float mnew = fmaxf(m_run, mx);
        float al = exp2f(m_run - mnew);
        m_run = mnew;
        l_run *= al;
        float al0 = __shfl(al, 4*lg + 0);
        float al1 = __shfl(al, 4*lg + 1);
        float al2 = __shfl(al, 4*lg + 2);
        float al3 = __shfl(al, 4*lg + 3);
#pragma unroll
        for (int n = 0; n < 16; n++) {
          acco[n][0] *= al0; acco[n][1] *= al1; acco[n][2] *= al2; acco[n][3] *= al3;
        }
      }
      float sum = 0.f;
#pragma unroll
      for (int i = 0; i < 8; i++) { sv[i] = exp2f(sv[i] - m_run); sum += sv[i]; }
      sum += __shfl_xor(sum, 16);
      sum += __shfl_xor(sum, 32);
      l_run += sum;
      // ---- P redistribution via shfl (replaces LDS ps; identical bf16 bits)
      // lane holds keys {4lg..4lg+3} in (w0,w1) and {16+4lg..+3} in (w2,w3);
      // lane needs keys {8lg..8lg+7}: sources sA (first 4) and sB (next 4),
      // lo words if lg<2 else hi words.
      bf16x8_t ap;
      {
        unsigned w0 = pack2(sv[0], sv[1]);
        unsigned w1 = pack2(sv[2], sv[3]);
        unsigned w2 = pack2(sv[4], sv[5]);
        unsigned w3 = pack2(sv[6], sv[7]);
        unsigned lo0 = __shfl(w0, sA), hi0 = __shfl(w2, sA);
        unsigned lo1 = __shfl(w1, sA), hi1 = __shfl(w3, sA);
        unsigned lo2 = __shfl(w0, sB), hi2 = __shfl(w2, sB);
        unsigned lo3 = __shfl(w1, sB), hi3 = __shfl(w3, sB);
        union { unsigned u[4]; bf16x8_t v; } apu;
        apu.u[0] = (lg < 2) ? lo0 : hi0;
        apu.u[1] = (lg < 2) ? lo1 : hi1;
        apu.u[2] = (lg < 2) ? lo2 : hi2;
        apu.u[3] = (lg < 2) ? lo3 : hi3;
        ap = apu.v;
      }
      // ---- PV (vt rows feature-major; row start banks tile all 32 banks)
#pragma unroll
      for (int n = 0; n < 16; n++) {
        bf16x8_t bv = *(const bf16x8_t*)&vtb[(16*n + lrow) * VPAD + lg * 8];
        acco[n] = __builtin_amdgcn_mfma_f32_16x16x32_bf16(ap, bv, acco[n], 0, 0, 0);
      }
      __syncthreads();                   // single barrier per tile
    }
    // ---- epilogue: normalize; 2-pass f32 o_lds; o @ wkv_b[h,64:,:]^T (f32 VALU, exact)
    float li = 1.f / l_run;
    float l0 = __shfl(li, 4*lg + 0);
    float l1 = __shfl(li, 4*lg + 1);
    float l2 = __shfl(li, 4*lg + 2);
    float l3 = __shfl(li, 4*lg + 3);
    int dx = t & 15, ty2 = t >> 4;
    float pr[4][4] = {};
    const float* wb2 = wkvb + (size_t)(h * 128 + 64) * 256;
#pragma unroll
    for (int p = 0; p < 2; p++) {
      __syncthreads();
#pragma unroll
      for (int n = 8*p; n < 8*p + 8; n++) {
        int fc = 16*n + lrow - 128*p;
        o_lds[(16*wv_ + 4*lg + 0) * OSTR2 + fc] = acco[n][0] * l0;
        o_lds[(16*wv_ + 4*lg + 1) * OSTR2 + fc] = acco[n][1] * l1;
        o_lds[(16*wv_ + 4*lg + 2) * OSTR2 + fc] = acco[n][2] * l2;
        o_lds[(16*wv_ + 4*lg + 3) * OSTR2 + fc] = acco[n][3] * l3;
      }
      __syncthreads();
      for (int c = 0; c < 128; c += 4) {
        float4 w0 = *(const float4*)(wb2 + (size_t)(dx*4 + 0) * 256 + 128*p + c);
        float4 w1 = *(const float4*)(wb2 + (size_t)(dx*4 + 1) * 256 + 128*p + c);
        float4 w2 = *(const float4*)(wb2 + (size_t)(dx*4 + 2) * 256 + 128*p + c);
        float4 w3 = *(const float4*)(wb2 + (size_t)(dx*4 + 3) * 256 + 128*p + c);
#pragma unroll
        for (int i = 0; i < 4; i++) {
          float4 ov = *(const float4*)&o_lds[(ty2*4 + i) * OSTR2 + c];
          pr[i][0] += ov.x*w0.x + ov.y*w0.y + ov.z*w0.z + ov.w*w0.w;
          pr[i][1] += ov.x*w1.x + ov.y*w1.y + ov.z*w1.z + ov.w*w1.w;
          pr[i][2] += ov.x*w2.x + ov.y*w2.y + ov.z*w2.z + ov.w*w2.w;
          pr[i][3] += ov.x*w3.x + ov.y*w3.y + ov.z*w3.z + ov.w*w3.w;
        }
      }
    }
#pragma unroll
    for (int i = 0; i < 4; i++)
#pragma unroll
      for (int j = 0; j < 4; j++)
        oproj[(size_t)(row0 + ty2*4 + i) * 1024 + h * 64 + dx*4 + j] = f2bfs(pr[i][j]);
  }
}

// ===================== top-2 gating + counts =====================
__global__ __launch_bounds__(256) void topk_kernel(
    const float* __restrict__ logits, int* __restrict__ tke,
    float* __restrict__ tkw, int* __restrict__ cnt)
{
  int tok = blockIdx.x * 256 + threadIdx.x;
  if (tok >= NTOK) return;
  float l[8];
#pragma unroll
  for (int e2 = 0; e2 < 8; e2++) l[e2] = logits[(size_t)tok * 8 + e2];
  float v0 = l[0]; int e0 = 0;
#pragma unroll
  for (int e2 = 1; e2 < 8; e2++) if (l[e2] > v0) { v0 = l[e2]; e0 = e2; }
  float v1 = -INFINITY; int e1 = 0;
#pragma unroll
  for (int e2 = 0; e2 < 8; e2++) if (e2 != e0 && l[e2] > v1) { v1 = l[e2]; e1 = e2; }
  float x = __expf(v1 - v0);
  float w0 = 1.f / (1.f + x);
  tke[tok * 2]     = e0; tke[tok * 2 + 1] = e1;
  tkw[tok * 2]     = w0; tkw[tok * 2 + 1] = 1.f - w0;
  atomicAdd(&cnt[e0], 1);
  atomicAdd(&cnt[8 + e1], 1);
}

__global__ void offsets_kernel(const int* cnt, int* base, int* pcnt)
{
  if (threadIdx.x == 0 && blockIdx.x == 0) {
    int cum = 0;
    for (int s2 = 0; s2 < 16; s2++) {
      int p = (cnt[s2] + 127) & ~127;
      base[s2] = cum; pcnt[s2] = p; cum += p;
    }
  }
}

__global__ __launch_bounds__(256) void scatter_kernel(
    const int* __restrict__ tke, const float* __restrict__ tkw,
    const int* __restrict__ base, int* cnt2,
    int* __restrict__ etok, float* __restrict__ ew)
{
  int tok = blockIdx.x * 256 + threadIdx.x;
  if (tok >= NTOK) return;
#pragma unroll
  for (int k = 0; k < 2; k++) {
    int e = tke[tok * 2 + k];
    int seg = k * 8 + e;
    int pos = atomicAdd(&cnt2[seg], 1);
    int row = base[seg] + pos;
    etok[row] = tok;
    ew[row] = tkw[tok * 2 + k];
  }
}

// ===================== MoE mlp1 v2 (all bf16): 128x64 tile, BK=64, 4 waves (2m x 2n) =======
__global__ __launch_bounds__(256, 3) void moe_mlp1_mfma(
    const unsigned short* __restrict__ Y,
    const unsigned short* __restrict__ Gp, const unsigned short* __restrict__ Up,
    const int* __restrict__ etok, const int* __restrict__ base,
    const int* __restrict__ pcnt, unsigned short* __restrict__ act)
{
  int seg = blockIdx.z;
  if ((int)(blockIdx.y * 128) >= pcnt[seg]) return;
  int e = seg & 7;
  __shared__ __align__(16) unsigned short As[128 * GSTR];
  __shared__ __align__(16) unsigned short Gs[64 * GSTR];
  __shared__ __align__(16) unsigned short Us[64 * GSTR];
  int t = threadIdx.x;
  int row0 = base[seg] + blockIdx.y * 128;
  int n0 = blockIdx.x * 64;
  int lane = t & 63, w = t >> 6;
  int mw = (w >> 1) * 64, nw = (w & 1) * 32;
  int lr = lane & 15, lg = lane >> 4;

  int srow = t >> 3, sc8 = (t & 7) * 8;
  int tokr[4];
#pragma unroll
  for (int it = 0; it < 4; it++) tokr[it] = etok[row0 + it*32 + srow];

  uint4 pa[4], pg[2], pu[2];
  auto ld = [&](int k0) {
#pragma unroll
    for (int it = 0; it < 4; it++)
      pa[it] = (tokr[it] >= 0)
        ? *(const uint4*)(Y + (size_t)tokr[it] * ND + k0 + sc8)
        : make_uint4(0u, 0u, 0u, 0u);
#pragma unroll
    for (int it = 0; it < 2; it++) {
      int r = n0 + it*32 + srow;
      pg[it] = *(const uint4*)(Gp + ((size_t)e * NFE + r) * ND + k0 + sc8);
      pu[it] = *(const uint4*)(Up + ((size_t)e * NFE + r) * ND + k0 + sc8);
    }
  };
  auto st = [&]() {
#pragma unroll
    for (int it = 0; it < 4; it++)
      *(uint4*)&As[(it*32 + srow) * GSTR + sc8] = pa[it];
#pragma unroll
    for (int it = 0; it < 2; it++) {
      *(uint4*)&Gs[(it*32 + srow) * GSTR + sc8] = pg[it];
      *(uint4*)&Us[(it*32 + srow) * GSTR + sc8] = pu[it];
    }
  };

  f32x4_t accg[4][2], accu[4][2];
#pragma unroll
  for (int i = 0; i < 4; i++)
#pragma unroll
    for (int j = 0; j < 2; j++) {
      accg[i][j] = (f32x4_t){0.f, 0.f, 0.f, 0.f};
      accu[i][j] = (f32x4_t){0.f, 0.f, 0.f, 0.f};
    }

  ld(0); st();
  __syncthreads();
  for (int k0 = 0; ; ) {
    int kn = k0 + 64;
    if (kn < ND) ld(kn);
#pragma unroll
    for (int kk = 0; kk < 2; kk++) {
      bf16x8_t af[4], gf[2], uf[2];
#pragma unroll
      for (int i = 0; i < 4; i++)
        af[i] = *(const bf16x8_t*)&As[(mw + 16*i + lr) * GSTR + kk*32 + lg*8];
#pragma unroll
      for (int j = 0; j < 2; j++) {
        gf[j] = *(const bf16x8_t*)&Gs[(nw + 16*j + lr) * GSTR + kk*32 + lg*8];
        uf[j] = *(const bf16x8_t*)&Us[(nw + 16*j + lr) * GSTR + kk*32 + lg*8];
      }
#pragma unroll
      for (int i = 0; i < 4; i++)
#pragma unroll
        for (int j = 0; j < 2; j++) {
          accg[i][j] = __builtin_amdgcn_mfma_f32_16x16x32_bf16(af[i], gf[j], accg[i][j], 0, 0, 0);
          accu[i][j] = __builtin_amdgcn_mfma_f32_16x16x32_bf16(af[i], uf[j], accu[i][j], 0, 0, 0);
        }
    }
    k0 = kn;
    if (k0 >= ND) break;
    __syncthreads();
    st();
    __syncthreads();
  }
#pragma unroll
  for (int i = 0; i < 4; i++)
#pragma unroll
    for (int j = 0; j < 2; j++) {
      int n = n0 + nw + 16*j + lr;
#pragma unroll
      for (int r = 0; r < 4; r++) {
        int m = row0 + mw + 16*i + 4*lg + r;
        float g = accg[i][j][r], u = accu[i][j][r];
        float s = g / (1.f + __expf(-g));
        act[(size_t)m * NFE + n] = f2bfs(s * u);
      }
    }
}

// ===================== MoE down v1 (all bf16): 128x128 tile, BK=64 =====================
__global__ __launch_bounds__(256) void moe_down_mfma(
    const unsigned short* __restrict__ act, const unsigned short* __restrict__ Dp,
    const int* __restrict__ etok, const float* __restrict__ ew,
    const int* __restrict__ base, const int* __restrict__ pcnt,
    int slot, float* __restrict__ out)
{
  int e = blockIdx.z;
  int seg = slot * 8 + e;
  if ((int)(blockIdx.y * 128) >= pcnt[seg]) return;
  __shared__ __align__(16) unsigned short As[128 * GSTR];
  __shared__ __align__(16) unsigned short Ws2[128 * GSTR];
  int t = threadIdx.x;
  int row0 = base[seg] + blockIdx.y * 128;
  int n0 = blockIdx.x * 128;
  int lane = t & 63, w = t >> 6;
  int mw = (w >> 1) * 64, nw = (w & 1) * 64;
  int lr = lane & 15, lg = lane >> 4;

  int srowv[4], sc8v[4];
#pragma unroll
  for (int it = 0; it < 4; it++) { int c = it*256 + t; srowv[it] = c >> 3; sc8v[it] = (c & 7) * 8; }

  uint4 pa[4], pw[4];
  auto ld = [&](int k0) {
#pragma unroll
    for (int it = 0; it < 4; it++) {
      pa[it] = *(const uint4*)(act + (size_t)(row0 + srowv[it]) * NFE + k0 + sc8v[it]);
      pw[it] = *(const uint4*)(Dp + ((size_t)e * ND + n0 + srowv[it]) * NFE + k0 + sc8v[it]);
    }
  };
  auto st = [&]() {
#pragma unroll
    for (int it = 0; it < 4; it++) {
      *(uint4*)&As[srowv[it] * GSTR + sc8v[it]] = pa[it];
      *(uint4*)&Ws2[srowv[it] * GSTR + sc8v[it]] = pw[it];
    }
  };

  f32x4_t acc[4][4];
#pragma unroll
  for (int i = 0; i < 4; i++)
#pragma unroll
    for (int j = 0; j < 4; j++) acc[i][j] = (f32x4_t){0.f, 0.f, 0.f, 0.f};

  ld(0); st();
  __syncthreads();
  for (int k0 = 0; ; ) {
    int kn = k0 + 64;
    if (kn < NFE) ld(kn);
#pragma unroll
    for (int kk = 0; kk < 2; kk++) {
      bf16x8_t af[4], wf[4];
#pragma unroll
      for (int i = 0; i < 4; i++)
        af[i] = *(const bf16x8_t*)&As[(mw + 16*i + lr) * GSTR + kk*32 + lg*8];
#pragma unroll
      for (int j = 0; j < 4; j++)
        wf[j] = *(const bf16x8_t*)&Ws2[(nw + 16*j + lr) * GSTR + kk*32 + lg*8];
#pragma unroll
      for (int i = 0; i < 4; i++)
#pragma unroll
        for (int j = 0; j < 4; j++)
          acc[i][j] = __builtin_amdgcn_mfma_f32_16x16x32_bf16(af[i], wf[j], acc[i][j], 0, 0, 0);
    }
    k0 = kn;
    if (k0 >= NFE) break;
    __syncthreads();
    st();
    __syncthreads();
  }
#pragma unroll
  for (int i = 0; i < 4; i++) {
    int tks[4]; float ews[4];
#pragma unroll
    for (int r = 0; r < 4; r++) {
      int rg = row0 + mw + 16*i + 4*lg + r;
      tks[r] = etok[rg]; ews[r] = ew[rg];
    }
#pragma unroll
    for (int j = 0; j < 4; j++) {
      int n = n0 + nw + 16*j + lr;
#pragma unroll
      for (int r = 0; r < 4; r++) {
        if (tks[r] >= 0)
          out[(size_t)tks[r] * ND + n] += ews[r] * acc[i][j][r];
      }
    }
  }
}

// ===================== launch =====================
extern "C" void kernel_launch(void* const* d_in, const int* in_sizes, int n_in,
                              void* d_out, int out_size, void* d_ws, size_t ws_size,
                              hipStream_t stream) {
  const float* hidden    = (const float*)d_in[0];
  const float* in_ln_w   = (const float*)d_in[2];
  const float* post_ln_w = (const float*)d_in[3];
  const float* wq_a_w    = (const float*)d_in[4];
  const float* wq_a_b    = (const float*)d_in[5];
  const float* q_norm_w  = (const float*)d_in[6];
  const float* wq_b_w    = (const float*)d_in[7];
  const float* wq_b_b    = (const float*)d_in[8];
  const float* wkv_a_w   = (const float*)d_in[9];
  const float* wkv_a_b   = (const float*)d_in[10];
  const float* kv_norm_w = (const float*)d_in[11];
  const float* wkv_b_w   = (const float*)d_in[12];
  const float* wo_w      = (const float*)d_in[13];
  const float* wo_b      = (const float*)d_in[14];
  const float* gate_w    = (const float*)d_in[15];
  const float* gate_b    = (const float*)d_in[16];
  const float* gate_proj = (const float*)d_in[17];
  const float* up_proj   = (const float*)d_in[18];
  const float* down_proj = (const float*)d_in[19];

  float* ws = (float*)d_ws;
  if (ws_size < WS_FLOATS * sizeof(float)) return;

  float* gwp = ws + OFF_GWP;
  float* tkw = ws + OFF_TKW;
  float* ew  = ws + OFF_EW;
  int* ib   = (int*)(ws + OFF_INT);
  int* tke  = ib;
  int* etok = ib + 8192;
  int* cnt  = ib + 8192 + ETOK_CAP;
  int* cnt2 = cnt + 16;
  int* base = cnt + 32;
  int* pcnt = cnt + 48;

  unsigned short* x_bf   = (unsigned short*)(ws + OFF_X);
  unsigned short* oproj  = (unsigned short*)(ws + OFF_X);
  unsigned short* ybuf   = (unsigned short*)(ws + OFF_X);
  float*          qa     = ws + OFF_QA;
  float*          qbuf   = ws + OFF_QA;
  unsigned short* gate_bf= (unsigned short*)(ws + OFF_GATE);
  unsigned short* down_bf= (unsigned short*)(ws + OFF_GATE);
  unsigned short* up_bf  = (unsigned short*)(ws + OFF_UP);
  unsigned short* qab    = (unsigned short*)(ws + OFF_QAB);
  float*          kvp    = ws + OFF_KVP;
  unsigned short* kvc    = (unsigned short*)(ws + OFF_KVC);
  unsigned short* actb   = (unsigned short*)(ws + OFF_ACT);
  unsigned short* wqa_bf = (unsigned short*)(ws + OFF_WA + WA_WQA);
  unsigned short* wqb_bf = (unsigned short*)(ws + OFF_WA + WA_WQB);
  unsigned short* wkva_bf= (unsigned short*)(ws + OFF_WA + WA_WKVA);
  unsigned short* wo_bf  = (unsigned short*)(ws + OFF_WA + WA_WO);

  float* out    = (float*)d_out;
  float* logits = out + (size_t)NTOK * ND;

  // ---- weight conversions (early set)
  conv_bf16_kernel<<<256, 256, 0, stream>>>(wq_a_w, wqa_bf, 524288);
  conv_bf16_kernel<<<144, 256, 0, stream>>>(wkv_a_w, wkva_bf, 294912);
  conv_bf16_kernel<<<384, 256, 0, stream>>>(wq_b_w, wqb_bf, 786432);
  conv_bf16_kernel<<<512, 256, 0, stream>>>(wo_w, wo_bf, 1048576);
  conv_gwp_kernel<<<32, 256, 0, stream>>>(gate_w, post_ln_w, gwp);

  // ---- forward
  rmsnorm_bf16<4><<<NTOK, 256, 0, stream>>>(hidden, ND, in_ln_w, x_bf, ND);
  gemm_bf16<false,false><<<dim3(4, 32), 256, 0, stream>>>(
      x_bf, ND, wqa_bf, ND, wq_a_b, nullptr, qa, 512, 512, ND);
  gemm_bf16<false,false><<<dim3(3, 32), 256, 0, stream>>>(
      x_bf, ND, wkva_bf, ND, wkv_a_b, nullptr, kvp, 288, 288, ND);
  rmsnorm_bf16<2><<<NTOK, 256, 0, stream>>>(qa, 512, q_norm_w, qab, 512);
  rmsnorm_bf16<1><<<NTOK, 256, 0, stream>>>(kvp, 288, kv_norm_w, kvc, 288);
  gemm_bf16<false,false><<<dim3(12, 32), 256, 0, stream>>>(
      qab, 512, wqb_bf, 512, wq_b_b, nullptr, qbuf, 1536, 1536, 512);
  rope_q_kernel<<<4096, 256, 0, stream>>>(qbuf);
  rope_k_kernel<<<256, 256, 0, stream>>>(kvp, kvc);
  {
    size_t smem = 78848;
    hipFuncSetAttribute((const void*)attn_kernel,
                        hipFuncAttributeMaxDynamicSharedMemorySize, (int)smem);
    attn_kernel<<<dim3(8, NH, NB), 256, smem, stream>>>(qbuf, kvc, wkv_b_w, oproj);
  }
  // qbuf/QAB/KVP/KVC regions dead -> MoE weight conversions
  conv_bf16_kernel<<<4096, 256, 0, stream>>>(gate_proj, gate_bf, 8388608);
  conv_bf16_kernel<<<4096, 256, 0, stream>>>(up_proj, up_bf, 8388608);
  // h = oproj @ wo^T + wo_b + hidden -> d_out (f32)
  gemm_bf16<false,true><<<dim3(8, 32), 256, 0, stream>>>(
      oproj, ND, wo_bf, ND, wo_b, hidden, out, ND, ND, ND);
  // fused post-LN rmsnorm (ybuf) + gate logits
  rms_gate_kernel<<<NTOK, 256, 0, stream>>>(out, post_ln_w, gwp, gate_b, ybuf, logits);
  hipMemsetAsync(cnt, 0, 32 * sizeof(int), stream);
  hipMemsetAsync(etok, 0xFF, ETOK_CAP * sizeof(int), stream);
  topk_kernel<<<16, 256, 0, stream>>>(logits, tke, tkw, cnt);
  offsets_kernel<<<1, 64, 0, stream>>>(cnt, base, pcnt);
  scatter_kernel<<<16, 256, 0, stream>>>(tke, tkw, base, cnt2, etok, ew);
  moe_mlp1_mfma<<<dim3(16, 32, 16), 256, 0, stream>>>(ybuf, gate_bf, up_bf,
                                                      etok, base, pcnt, actb);
  // gate_bf dead -> down_bf conversion
  conv_bf16_kernel<<<4096, 256, 0, stream>>>(down_proj, down_bf, 8388608);
  moe_down_mfma<<<dim3(8, 32, 8), 256, 0, stream>>>(actb, down_bf, etok, ew,
                                                    base, pcnt, 0, out);
  moe_down_mfma<<<dim3(8, 32, 8), 256, 0, stream>>>(actb, down_bf, etok, ew,
                                                    base, pcnt, 1, out);
}

// Round 22
// 907.349 us; speedup vs baseline: 1.0041x; 1.0041x over previous
//
#include <hip/hip_runtime.h>
#include <math.h>

// ===== problem constants =====
#define NB   4
#define NS   1024
#define ND   1024
#define NH   16
#define NTOK 4096
#define NFE  1024
#define ETOK_CAP 10240

// (1/sqrt(96)) * log2(e) — applied to q at attention prologue load; scores in log2 domain
#define SCL_LOG2E 0.14724445f

// ===== workspace layout (f32 slot offsets) =====
static constexpr size_t OFF_GWP  = 0;          // 8,192
static constexpr size_t OFF_TKW  = 8192;       // 8,192
static constexpr size_t OFF_EW   = 16384;      // 10,240 (ends 26,624)
static constexpr size_t OFF_INT  = 26624;      // 18,496 ints = 18,496 slots (ends 45,120)
static constexpr size_t OFF_X    = 45184;      // 2,097,152: x_bf -> oproj -> ybuf (ends 2,142,336)
static constexpr size_t OFF_QA   = 2142336;    // qa f32 2M -> qbuf f32 6,291,456 (ends 8,433,792)
static constexpr size_t OFF_GATE = 2142336;    // gate_bf 4,194,304 (after attn); later down_bf
static constexpr size_t OFF_UP   = 6336640;    // up_bf 4,194,304 (after attn; ends 10,530,944)
static constexpr size_t OFF_QAB  = 8433792;    // qab bf16 1,048,576
static constexpr size_t OFF_KVP  = 9482368;    // kvp f32 1,179,648 (ends 10,662,016)
static constexpr size_t OFF_KVC  = 10662016;   // kvc bf16 589,824 (ends 11,251,840)
static constexpr size_t OFF_WA   = 11251840;   // weight pool 1,327,104 (dead after wo-gemm)
static constexpr size_t WA_WQA   = 0;
static constexpr size_t WA_WQB   = 262144;
static constexpr size_t WA_WKVA  = 655360;
static constexpr size_t WA_WO    = 802816;
static constexpr size_t OFF_ACT  = 10530944;   // actb bf16 5,242,880 (ends 15,773,824)
static constexpr size_t WS_FLOATS = 15773824;

typedef __attribute__((ext_vector_type(8))) short bf16x8_t;
typedef __attribute__((ext_vector_type(4))) float f32x4_t;

__device__ __forceinline__ unsigned pack2(float a, float b) {
  union { float f; unsigned u; } x, y; x.f = a; y.f = b;
  unsigned lo = (x.u + 0x7fffu + ((x.u >> 16) & 1u)) >> 16;
  unsigned hi = (y.u + 0x7fffu + ((y.u >> 16) & 1u)) & 0xffff0000u;
  return (lo & 0xffffu) | hi;
}
__device__ __forceinline__ unsigned short f2bfs(float f) {
  union { float f; unsigned u; } x; x.f = f;
  return (unsigned short)((x.u + 0x7fffu + ((x.u >> 16) & 1u)) >> 16);
}

// ===================== f32 -> bf16 conversion =====================
__global__ __launch_bounds__(256) void conv_bf16_kernel(
    const float* __restrict__ src, unsigned short* __restrict__ dst, int n)
{
  int i = (blockIdx.x * 256 + threadIdx.x) * 8;
  if (i >= n) return;
  float4 a = *(const float4*)(src + i);
  float4 b = *(const float4*)(src + i + 4);
  uint4 o;
  o.x = pack2(a.x, a.y); o.y = pack2(a.z, a.w);
  o.z = pack2(b.x, b.y); o.w = pack2(b.z, b.w);
  *(uint4*)(dst + i) = o;
}

// gwp[e][d] = gate_w[e][d] * post_ln_w[d]
__global__ __launch_bounds__(256) void conv_gwp_kernel(
    const float* __restrict__ gw, const float* __restrict__ pw, float* __restrict__ gwp)
{
  int i = blockIdx.x * 256 + threadIdx.x;
  gwp[i] = gw[i] * pw[i & 1023];
}

// ===================== RMSNorm (f32 in -> bf16 out) =====================
template<int PER>
__global__ __launch_bounds__(256) void rmsnorm_bf16(
    const float* in, int istr, const float* w, unsigned short* out, int ostr)
{
  int row = blockIdx.x, t = threadIdx.x;
  const float* ip = in + (size_t)row * istr;
  float v[PER];
  float ss = 0.f;
#pragma unroll
  for (int i = 0; i < PER; i++) { v[i] = ip[t + i*256]; ss += v[i]*v[i]; }
#pragma unroll
  for (int k = 1; k < 64; k <<= 1) ss += __shfl_xor(ss, k);
  __shared__ float red[4];
  if ((t & 63) == 0) red[t >> 6] = ss;
  __syncthreads();
  float tot = red[0] + red[1] + red[2] + red[3];
  float inv = rsqrtf(tot * (1.f / (PER * 256)) + 1e-6f);
  unsigned short* op = out + (size_t)row * ostr;
#pragma unroll
  for (int i = 0; i < PER; i++) op[t + i*256] = f2bfs(v[i] * inv * w[t + i*256]);
}

// ===================== fused kv rmsnorm (cols 0..255) + rope_k (cols 256..287) ==========
// Arithmetic verbatim from rmsnorm_bf16<1> and rope_k_kernel -> bit-identical kvc.
__global__ __launch_bounds__(256) void rmsnorm_rope_kv(
    const float* __restrict__ kvp, const float* __restrict__ w,
    unsigned short* __restrict__ kvc)
{
  int row = blockIdx.x, t = threadIdx.x;
  const float* ip = kvp + (size_t)row * 288;
  float v = ip[t];
  float ss = v * v;
#pragma unroll
  for (int k = 1; k < 64; k <<= 1) ss += __shfl_xor(ss, k);
  __shared__ float red[4];
  if ((t & 63) == 0) red[t >> 6] = ss;
  __syncthreads();
  float tot = red[0] + red[1] + red[2] + red[3];
  float inv = rsqrtf(tot * (1.f / 256.f) + 1e-6f);
  unsigned short* op = kvc + (size_t)row * 288;
  op[t] = f2bfs(v * inv * w[t]);
  if (t < 16) {
    int s = row & (NS - 1);
    float invf = __expf(-(float)(2 * t) * (9.210340371976184f / 32.f));
    float fr = (float)s * invf;
    float sn, cs; sincosf(fr, &sn, &cs);
    float x1 = ip[256 + t], x2 = ip[256 + t + 16];
    op[256 + t]      = f2bfs(x1 * cs - x2 * sn);
    op[256 + t + 16] = f2bfs(x2 * cs + x1 * sn);
  }
}

// ===================== fused post-LN rmsnorm + gate logits =====================
__global__ __launch_bounds__(256) void rms_gate_kernel(
    const float* __restrict__ H, const float* __restrict__ pw,
    const float* __restrict__ gwp, const float* __restrict__ gb,
    unsigned short* __restrict__ ybuf, float* __restrict__ logits)
{
  __shared__ __align__(16) float ly[1024];
  __shared__ float red[4];
  int tok = blockIdx.x, t = threadIdx.x;
  float4 hv = *(const float4*)(H + (size_t)tok * ND + t * 4);
  *(float4*)&ly[t * 4] = hv;
  float ss = hv.x*hv.x + hv.y*hv.y + hv.z*hv.z + hv.w*hv.w;
#pragma unroll
  for (int k = 1; k < 64; k <<= 1) ss += __shfl_xor(ss, k);
  if ((t & 63) == 0) red[t >> 6] = ss;
  __syncthreads();
  float inv = rsqrtf((red[0] + red[1] + red[2] + red[3]) * (1.f / 1024.f) + 1e-6f);
  float4 pw4 = *(const float4*)(pw + t * 4);
  unsigned short* yb = ybuf + (size_t)tok * ND + t * 4;
  yb[0] = f2bfs((hv.x * inv) * pw4.x);
  yb[1] = f2bfs((hv.y * inv) * pw4.y);
  yb[2] = f2bfs((hv.z * inv) * pw4.z);
  yb[3] = f2bfs((hv.w * inv) * pw4.w);
  int e = t >> 5, lane = t & 31;
  const float* w = gwp + (size_t)e * ND;
  float acc = 0.f;
  for (int d = lane; d < ND; d += 32) acc += ly[d] * w[d];
#pragma unroll
  for (int k = 16; k >= 1; k >>= 1) acc += __shfl_xor(acc, k);
  if (lane == 0) logits[(size_t)tok * 8 + e] = acc * inv + gb[e];
}

// ===================== bf16 MFMA GEMM: C = A @ W^T + bias (+resid) =====================
#define GSTR 72

template<bool OUTBF, bool RESID>
__global__ __launch_bounds__(256) void gemm_bf16(
    const unsigned short* __restrict__ A, int lda,
    const unsigned short* __restrict__ W, int ldw,
    const float* __restrict__ bias,
    const float* __restrict__ resid,
    void* __restrict__ Cv, int ldc, int N, int K)
{
  __shared__ __align__(16) unsigned short As[128 * GSTR];
  __shared__ __align__(16) unsigned short Ws2[128 * GSTR];
  int t = threadIdx.x;
  int m0 = blockIdx.y * 128, n0 = blockIdx.x * 128;
  int lane = t & 63, w = t >> 6;
  int mw = (w >> 1) * 64, nw = (w & 1) * 64;
  int lr = lane & 15, lg = lane >> 4;

  int srowv[4], sc8v[4];
#pragma unroll
  for (int it = 0; it < 4; it++) { int c = it*256 + t; srowv[it] = c >> 3; sc8v[it] = (c & 7) * 8; }

  uint4 pa[4], pw[4];
  auto ld = [&](int k0) {
#pragma unroll
    for (int it = 0; it < 4; it++) {
      pa[it] = *(const uint4*)(A + (size_t)(m0 + srowv[it]) * lda + k0 + sc8v[it]);
      int r = n0 + srowv[it];
      pw[it] = (r < N) ? *(const uint4*)(W + (size_t)r * ldw + k0 + sc8v[it])
                       : make_uint4(0u, 0u, 0u, 0u);
    }
  };
  auto st = [&]() {
#pragma unroll
    for (int it = 0; it < 4; it++) {
      *(uint4*)&As[srowv[it] * GSTR + sc8v[it]] = pa[it];
      *(uint4*)&Ws2[srowv[it] * GSTR + sc8v[it]] = pw[it];
    }
  };

  f32x4_t acc[4][4];
#pragma unroll
  for (int i = 0; i < 4; i++)
#pragma unroll
    for (int j = 0; j < 4; j++) acc[i][j] = (f32x4_t){0.f, 0.f, 0.f, 0.f};

  ld(0); st();
  __syncthreads();
  for (int k0 = 0; ; ) {
    int kn = k0 + 64;
    if (kn < K) ld(kn);
#pragma unroll
    for (int kk = 0; kk < 2; kk++) {
      bf16x8_t af[4], wf[4];
#pragma unroll
      for (int i = 0; i < 4; i++)
        af[i] = *(const bf16x8_t*)&As[(mw + 16*i + lr) * GSTR + kk*32 + lg*8];
#pragma unroll
      for (int j = 0; j < 4; j++)
        wf[j] = *(const bf16x8_t*)&Ws2[(nw + 16*j + lr) * GSTR + kk*32 + lg*8];
#pragma unroll
      for (int i = 0; i < 4; i++)
#pragma unroll
        for (int j = 0; j < 4; j++)
          acc[i][j] = __builtin_amdgcn_mfma_f32_16x16x32_bf16(af[i], wf[j], acc[i][j], 0, 0, 0);
    }
    k0 = kn;
    if (k0 >= K) break;
    __syncthreads();
    st();
    __syncthreads();
  }
#pragma unroll
  for (int j = 0; j < 4; j++) {
    int n = n0 + nw + 16*j + lr;
    if (n < N) {
      float bv = bias[n];
#pragma unroll
      for (int i = 0; i < 4; i++) {
#pragma unroll
        for (int r = 0; r < 4; r++) {
          int m = m0 + mw + 16*i + 4*lg + r;
          size_t off = (size_t)m * ldc + n;
          float v = acc[i][j][r] + bv;
          if (RESID) v += resid[off];
          if (OUTBF) ((unsigned short*)Cv)[off] = f2bfs(v);
          else       ((float*)Cv)[off] = v;
        }
      }
    }
  }
}

// ===================== RoPE (f32 qbuf) =====================
__global__ __launch_bounds__(256) void rope_q_kernel(float* qbuf)
{
  int id = blockIdx.x * 256 + threadIdx.x;     // NTOK*NH*16
  int d = id & 15;
  int h = (id >> 4) & 15;
  int sr = id >> 8;
  int s = sr & (NS - 1);
  float inv = __expf(-(float)(2 * d) * (9.210340371976184f / 32.f));
  float fr = (float)s * inv;
  float sn, cs; sincosf(fr, &sn, &cs);
  float* p = qbuf + (size_t)sr * 1536 + h * 96 + 64;
  float x1 = p[d], x2 = p[d + 16];
  p[d]      = x1 * cs - x2 * sn;
  p[d + 16] = x2 * cs + x1 * sn;
}

// ===================== MLA flash attention v8 — EXACT R12/R14/R17 kernel =====================
// Paired q-tiles {15-bx, bx} per block -> uniform 34 tiles/block; grid 512 = 2 blocks/CU.
// V staged by per-feature gather; exact f32 prologue/epilogue. dynamic LDS 54,528 B.
#define KSTR 296
#define QNSTR 65
#define VPAD 40
#define OSTR2 132

__global__ __launch_bounds__(256, 2) void attn_kernel(
    const float* __restrict__ qbuf,           // (NTOK,1536) f32 post-rope
    const unsigned short* __restrict__ kvc,   // (NTOK,288) bf16
    const float* __restrict__ wkvb,           // (H*128,256) f32
    unsigned short* __restrict__ oproj)       // (NTOK,1024) bf16
{
  extern __shared__ float4 smem_f4[];
  unsigned short* sm  = (unsigned short*)smem_f4;
  unsigned short* ks  = sm;             // [32][KSTR] loop
  unsigned short* vt  = sm + 9472;      // [256][VPAD] loop
  unsigned short* ps  = sm + 19712;     // [64][32] loop
  float* qn           = (float*)sm;     // [64][QNSTR] prologue
  unsigned short* qst = sm + 8320;      // [64][KSTR] prologue
  float* o_lds        = (float*)sm;     // [64][OSTR2] epilogue

  int bx = blockIdx.x;                  // 0..7
  int h = blockIdx.y, b = blockIdx.z;
  int t = threadIdx.x;
  int lane = t & 63, wv_ = t >> 6;
  int lrow = lane & 15, lg = lane >> 4;
  int qrow = 16 * wv_ + lrow;

  int srow[5], sc16[5];
#pragma unroll
  for (int it = 0; it < 5; it++) {
    int c = it * 256 + t;
    srow[it] = c / 36; sc16[it] = c % 36;
  }
  bool tail = (t < 128);

  for (int half = 0; half < 2; half++) {
    int qb = half ? bx : (15 - bx);     // heavy tile first
    int row0 = b * NS + qb * 64;
    __syncthreads();                    // previous half's LDS fully consumed

    // ---- prologue a: q_nope (f32, scaled) -> qn ; q_pe -> bq[8]
    for (int idx = t; idx < 4096; idx += 256) {
      int r = idx >> 6, c = idx & 63;
      qn[r * QNSTR + c] = qbuf[(size_t)(row0 + r) * 1536 + h * 96 + c] * SCL_LOG2E;
    }
    bf16x8_t bq[9];
    {
      const float* src = qbuf + (size_t)(row0 + qrow) * 1536 + h * 96 + 64 + lg * 8;
      unsigned short* bp = (unsigned short*)&bq[8];
#pragma unroll
      for (int j = 0; j < 8; j++) bp[j] = f2bfs(src[j] * SCL_LOG2E);
    }
    __syncthreads();
    // ---- prologue b: q_abs = q_nope @ wkv_b[h,0:64,:]  (f32 VALU, exact)
    {
      int cx = t & 63, ry = t >> 6;
      float a[16][4] = {};
      const float* wb = wkvb + (size_t)h * 32768 + cx * 4;
      for (int k = 0; k < 64; k++) {
        float4 wv = *(const float4*)(wb + (size_t)k * 256);
#pragma unroll
        for (int r = 0; r < 16; r++) {
          float qv = qn[(ry * 16 + r) * QNSTR + k];
          a[r][0] += qv * wv.x; a[r][1] += qv * wv.y; a[r][2] += qv * wv.z; a[r][3] += qv * wv.w;
        }
      }
      __syncthreads();   // qn reads done before qst (overlapping region) is written
#pragma unroll
      for (int r = 0; r < 16; r++) {
        uint2 pk; pk.x = pack2(a[r][0], a[r][1]); pk.y = pack2(a[r][2], a[r][3]);
        *(uint2*)&qst[(ry * 16 + r) * KSTR + cx * 4] = pk;
      }
    }
    __syncthreads();
#pragma unroll
    for (int kk = 0; kk < 8; kk++)
      bq[kk] = *(const bf16x8_t*)&qst[qrow * KSTR + kk * 32 + lg * 8];
    __syncthreads();

    // ---- loop state
    float m_run = -1e30f, l_run = 0.f;
    f32x4_t acco[16];
#pragma unroll
    for (int n = 0; n < 16; n++) acco[n] = (f32x4_t){0.f, 0.f, 0.f, 0.f};

    uint4 pa[5];
    unsigned short vg[32];

    auto issue = [&](int kb2) {
      const unsigned short* tb = kvc + ((size_t)b * NS + kb2 * 32) * 288;
#pragma unroll
      for (int it = 0; it < 4; it++)
        pa[it] = *(const uint4*)(tb + srow[it] * 288 + sc16[it] * 8);
      if (tail) pa[4] = *(const uint4*)(tb + srow[4] * 288 + sc16[4] * 8);
      const unsigned short* vsrc = tb + t;   // feature t, keys 0..31
#pragma unroll
      for (int k = 0; k < 32; k++) vg[k] = vsrc[k * 288];
    };
    auto commit = [&]() {
#pragma unroll
      for (int it = 0; it < 5; it++) {
        if (it == 4 && !tail) continue;
        *(uint4*)&ks[srow[it] * KSTR + sc16[it] * 8] = pa[it];
      }
      unsigned wds[16];
#pragma unroll
      for (int j = 0; j < 16; j++)
        wds[j] = (unsigned)vg[2*j] | ((unsigned)vg[2*j+1] << 16);
#pragma unroll
      for (int j = 0; j < 4; j++)
        *(uint4*)&vt[t * VPAD + j * 8] =
          make_uint4(wds[4*j], wds[4*j+1], wds[4*j+2], wds[4*j+3]);
    };

    int nkb = 2 * qb + 2;
    issue(0); commit();
    __syncthreads();
    for (int kb = 0; kb < nkb; kb++) {
      bool more = (kb + 1 < nkb);
      if (more) issue(kb + 1);
      int key0 = kb * 32;
      // ---- scores (even/odd chains), K-dim 288
      f32x4_t s0e = {0.f,0.f,0.f,0.f}, s0o = {0.f,0.f,0.f,0.f};
      f32x4_t s1e = {0.f,0.f,0.f,0.f}, s1o = {0.f,0.f,0.f,0.f};
#pragma unroll
      for (int kk = 0; kk < 9; kk++) {
        bf16x8_t a0 = *(const bf16x8_t*)&ks[lrow * KSTR + kk*32 + lg*8];
        bf16x8_t a1 = *(const bf16x8_t*)&ks[(16 + lrow) * KSTR + kk*32 + lg*8];
        if (kk & 1) {
          s0o = __builtin_amdgcn_mfma_f32_16x16x32_bf16(a0, bq[kk], s0o, 0, 0, 0);
          s1o = __builtin_amdgcn_mfma_f32_16x16x32_bf16(a1, bq[kk], s1o, 0, 0, 0);
        } else {
          s0e = __builtin_amdgcn_mfma_f32_16x16x32_bf16(a0, bq[kk], s0e, 0, 0, 0);
          s1e = __builtin_amdgcn_mfma_f32_16x16x32_bf16(a1, bq[kk], s1e, 0, 0, 0);
        }
      }
      f32x4_t s0a = s0e + s0o, s1a = s1e + s1o;
      // ---- causal mask (skipped on full tiles) + online softmax in log2 domain
      int qg = qb * 64 + qrow;
      float sv[8];
      if (key0 + 31 > qb * 64 + 16 * wv_) {
#pragma unroll
        for (int r = 0; r < 4; r++) {
          sv[r]     = (key0 + 4*lg + r      <= qg) ? s0a[r] : -1e30f;
          sv[4 + r] = (key0 + 16 + 4*lg + r <= qg) ? s1a[r] : -1e30f;
        }
      } else {
#pragma unroll
        for (int r = 0; r < 4; r++) { sv[r] = s0a[r]; sv[4 + r] = s1a[r]; }
      }
      float mx = sv[0];
#pragma unroll
      for (int i = 1; i < 8; i++) mx = fmaxf(mx, sv[i]);
      mx = fmaxf(mx, __shfl_xor(mx, 16));
      mx = fmaxf(mx, __shfl_xor(mx, 32));
      if (!__all(mx - m_run <= 11.0f)) {   // defer-max (T13)
        float mnew = fmaxf(m_run, mx);
        float al = exp2f(m_run - mnew);
        m_run = mnew;
        l_run *= al;
        float al0 = __shfl(al, 4*lg + 0);
        float al1 = __shfl(al, 4*lg + 1);
        float al2 = __shfl(al, 4*lg + 2);
        float al3 = __shfl(al, 4*lg + 3);
#pragma unroll
        for (int n = 0; n < 16; n++) {
          acco[n][0] *= al0; acco[n][1] *= al1; acco[n][2] *= al2; acco[n][3] *= al3;
        }
      }
      float sum = 0.f;
#pragma unroll
      for (int i = 0; i < 8; i++) { sv[i] = exp2f(sv[i] - m_run); sum += sv[i]; }
      sum += __shfl_xor(sum, 16);
      sum += __shfl_xor(sum, 32);
      l_run += sum;
      // ---- P -> ps (bf16, XOR-swizzled 16B granules)
      {
        int swz = qrow & 3;
        int g0 = lg >> 1, h0 = lg & 1;
        uint2 p0; p0.x = pack2(sv[0], sv[1]); p0.y = pack2(sv[2], sv[3]);
        uint2 p1; p1.x = pack2(sv[4], sv[5]); p1.y = pack2(sv[6], sv[7]);
        char* pr = (char*)ps + qrow * 64;
        *(uint2*)(pr + ((g0 ^ swz) * 16 + h0 * 8))       = p0;
        *(uint2*)(pr + (((2 + g0) ^ swz) * 16 + h0 * 8)) = p1;
      }
      // ---- PV (vt rows feature-major; row start banks tile all 32 banks)
      {
        bf16x8_t ap = *(const bf16x8_t*)((char*)ps + qrow * 64 + ((lg ^ (qrow & 3)) * 16));
#pragma unroll
        for (int n = 0; n < 16; n++) {
          bf16x8_t bv = *(const bf16x8_t*)&vt[(16*n + lrow) * VPAD + lg * 8];
          acco[n] = __builtin_amdgcn_mfma_f32_16x16x32_bf16(ap, bv, acco[n], 0, 0, 0);
        }
      }
      __syncthreads();
      if (more) { commit(); __syncthreads(); }
    }
    // ---- epilogue: normalize; 2-pass f32 o_lds; o @ wkv_b[h,64:,:]^T (f32 VALU, exact)
    float li = 1.f / l_run;
    float l0 = __shfl(li, 4*lg + 0);
    float l1 = __shfl(li, 4*lg + 1);
    float l2 = __shfl(li, 4*lg + 2);
    float l3 = __shfl(li, 4*lg + 3);
    int dx = t & 15, ty2 = t >> 4;
    float pr[4][4] = {};
    const float* wb2 = wkvb + (size_t)(h * 128 + 64) * 256;
#pragma unroll
    for (int p = 0; p < 2; p++) {
      __syncthreads();
#pragma unroll
      for (int n = 8*p; n < 8*p + 8; n++) {
        int fc = 16*n + lrow - 128*p;
        o_lds[(16*wv_ + 4*lg + 0) * OSTR2 + fc] = acco[n][0] * l0;
        o_lds[(16*wv_ + 4*lg + 1) * OSTR2 + fc] = acco[n][1] * l1;
        o_lds[(16*wv_ + 4*lg + 2) * OSTR2 + fc] = acco[n][2] * l2;
        o_lds[(16*wv_ + 4*lg + 3) * OSTR2 + fc] = acco[n][3] * l3;
      }
      __syncthreads();
      for (int c = 0; c < 128; c += 4) {
        float4 w0 = *(const float4*)(wb2 + (size_t)(dx*4 + 0) * 256 + 128*p + c);
        float4 w1 = *(const float4*)(wb2 + (size_t)(dx*4 + 1) * 256 + 128*p + c);
        float4 w2 = *(const float4*)(wb2 + (size_t)(dx*4 + 2) * 256 + 128*p + c);
        float4 w3 = *(const float4*)(wb2 + (size_t)(dx*4 + 3) * 256 + 128*p + c);
#pragma unroll
        for (int i = 0; i < 4; i++) {
          float4 ov = *(const float4*)&o_lds[(ty2*4 + i) * OSTR2 + c];
          pr[i][0] += ov.x*w0.x + ov.y*w0.y + ov.z*w0.z + ov.w*w0.w;
          pr[i][1] += ov.x*w1.x + ov.y*w1.y + ov.z*w1.z + ov.w*w1.w;
          pr[i][2] += ov.x*w2.x + ov.y*w2.y + ov.z*w2.z + ov.w*w2.w;
          pr[i][3] += ov.x*w3.x + ov.y*w3.y + ov.z*w3.z + ov.w*w3.w;
        }
      }
    }
#pragma unroll
    for (int i = 0; i < 4; i++)
#pragma unroll
      for (int j = 0; j < 4; j++)
        oproj[(size_t)(row0 + ty2*4 + i) * 1024 + h * 64 + dx*4 + j] = f2bfs(pr[i][j]);
  }
}

// ===================== top-2 gating + counts =====================
__global__ __launch_bounds__(256) void topk_kernel(
    const float* __restrict__ logits, int* __restrict__ tke,
    float* __restrict__ tkw, int* __restrict__ cnt)
{
  int tok = blockIdx.x * 256 + threadIdx.x;
  if (tok >= NTOK) return;
  float l[8];
#pragma unroll
  for (int e2 = 0; e2 < 8; e2++) l[e2] = logits[(size_t)tok * 8 + e2];
  float v0 = l[0]; int e0 = 0;
#pragma unroll
  for (int e2 = 1; e2 < 8; e2++) if (l[e2] > v0) { v0 = l[e2]; e0 = e2; }
  float v1 = -INFINITY; int e1 = 0;
#pragma unroll
  for (int e2 = 0; e2 < 8; e2++) if (e2 != e0 && l[e2] > v1) { v1 = l[e2]; e1 = e2; }
  float x = __expf(v1 - v0);
  float w0 = 1.f / (1.f + x);
  tke[tok * 2]     = e0; tke[tok * 2 + 1] = e1;
  tkw[tok * 2]     = w0; tkw[tok * 2 + 1] = 1.f - w0;
  atomicAdd(&cnt[e0], 1);
  atomicAdd(&cnt[8 + e1], 1);
}

__global__ void offsets_kernel(const int* cnt, int* base, int* pcnt)
{
  if (threadIdx.x == 0 && blockIdx.x == 0) {
    int cum = 0;
    for (int s2 = 0; s2 < 16; s2++) {
      int p = (cnt[s2] + 127) & ~127;
      base[s2] = cum; pcnt[s2] = p; cum += p;
    }
  }
}

__global__ __launch_bounds__(256) void scatter_kernel(
    const int* __restrict__ tke, const float* __restrict__ tkw,
    const int* __restrict__ base, int* cnt2,
    int* __restrict__ etok, float* __restrict__ ew)
{
  int tok = blockIdx.x * 256 + threadIdx.x;
  if (tok >= NTOK) return;
#pragma unroll
  for (int k = 0; k < 2; k++) {
    int e = tke[tok * 2 + k];
    int seg = k * 8 + e;
    int pos = atomicAdd(&cnt2[seg], 1);
    int row = base[seg] + pos;
    etok[row] = tok;
    ew[row] = tkw[tok * 2 + k];
  }
}

// ===================== MoE mlp1 v2 (all bf16): 128x64 tile, BK=64, 4 waves (2m x 2n) =======
__global__ __launch_bounds__(256, 3) void moe_mlp1_mfma(
    const unsigned short* __restrict__ Y,
    const unsigned short* __restrict__ Gp, const unsigned short* __restrict__ Up,
    const int* __restrict__ etok, const int* __restrict__ base,
    const int* __restrict__ pcnt, unsigned short* __restrict__ act)
{
  int seg = blockIdx.z;
  if ((int)(blockIdx.y * 128) >= pcnt[seg]) return;
  int e = seg & 7;
  __shared__ __align__(16) unsigned short As[128 * GSTR];
  __shared__ __align__(16) unsigned short Gs[64 * GSTR];
  __shared__ __align__(16) unsigned short Us[64 * GSTR];
  int t = threadIdx.x;
  int row0 = base[seg] + blockIdx.y * 128;
  int n0 = blockIdx.x * 64;
  int lane = t & 63, w = t >> 6;
  int mw = (w >> 1) * 64, nw = (w & 1) * 32;
  int lr = lane & 15, lg = lane >> 4;

  int srow = t >> 3, sc8 = (t & 7) * 8;
  int tokr[4];
#pragma unroll
  for (int it = 0; it < 4; it++) tokr[it] = etok[row0 + it*32 + srow];

  uint4 pa[4], pg[2], pu[2];
  auto ld = [&](int k0) {
#pragma unroll
    for (int it = 0; it < 4; it++)
      pa[it] = (tokr[it] >= 0)
        ? *(const uint4*)(Y + (size_t)tokr[it] * ND + k0 + sc8)
        : make_uint4(0u, 0u, 0u, 0u);
#pragma unroll
    for (int it = 0; it < 2; it++) {
      int r = n0 + it*32 + srow;
      pg[it] = *(const uint4*)(Gp + ((size_t)e * NFE + r) * ND + k0 + sc8);
      pu[it] = *(const uint4*)(Up + ((size_t)e * NFE + r) * ND + k0 + sc8);
    }
  };
  auto st = [&]() {
#pragma unroll
    for (int it = 0; it < 4; it++)
      *(uint4*)&As[(it*32 + srow) * GSTR + sc8] = pa[it];
#pragma unroll
    for (int it = 0; it < 2; it++) {
      *(uint4*)&Gs[(it*32 + srow) * GSTR + sc8] = pg[it];
      *(uint4*)&Us[(it*32 + srow) * GSTR + sc8] = pu[it];
    }
  };

  f32x4_t accg[4][2], accu[4][2];
#pragma unroll
  for (int i = 0; i < 4; i++)
#pragma unroll
    for (int j = 0; j < 2; j++) {
      accg[i][j] = (f32x4_t){0.f, 0.f, 0.f, 0.f};
      accu[i][j] = (f32x4_t){0.f, 0.f, 0.f, 0.f};
    }

  ld(0); st();
  __syncthreads();
  for (int k0 = 0; ; ) {
    int kn = k0 + 64;
    if (kn < ND) ld(kn);
#pragma unroll
    for (int kk = 0; kk < 2; kk++) {
      bf16x8_t af[4], gf[2], uf[2];
#pragma unroll
      for (int i = 0; i < 4; i++)
        af[i] = *(const bf16x8_t*)&As[(mw + 16*i + lr) * GSTR + kk*32 + lg*8];
#pragma unroll
      for (int j = 0; j < 2; j++) {
        gf[j] = *(const bf16x8_t*)&Gs[(nw + 16*j + lr) * GSTR + kk*32 + lg*8];
        uf[j] = *(const bf16x8_t*)&Us[(nw + 16*j + lr) * GSTR + kk*32 + lg*8];
      }
#pragma unroll
      for (int i = 0; i < 4; i++)
#pragma unroll
        for (int j = 0; j < 2; j++) {
          accg[i][j] = __builtin_amdgcn_mfma_f32_16x16x32_bf16(af[i], gf[j], accg[i][j], 0, 0, 0);
          accu[i][j] = __builtin_amdgcn_mfma_f32_16x16x32_bf16(af[i], uf[j], accu[i][j], 0, 0, 0);
        }
    }
    k0 = kn;
    if (k0 >= ND) break;
    __syncthreads();
    st();
    __syncthreads();
  }
#pragma unroll
  for (int i = 0; i < 4; i++)
#pragma unroll
    for (int j = 0; j < 2; j++) {
      int n = n0 + nw + 16*j + lr;
#pragma unroll
      for (int r = 0; r < 4; r++) {
        int m = row0 + mw + 16*i + 4*lg + r;
        float g = accg[i][j][r], u = accu[i][j][r];
        float s = g / (1.f + __expf(-g));
        act[(size_t)m * NFE + n] = f2bfs(s * u);
      }
    }
}

// ===================== MoE down v1 (all bf16): 128x128 tile, BK=64 =====================
__global__ __launch_bounds__(256) void moe_down_mfma(
    const unsigned short* __restrict__ act, const unsigned short* __restrict__ Dp,
    const int* __restrict__ etok, const float* __restrict__ ew,
    const int* __restrict__ base, const int* __restrict__ pcnt,
    int slot, float* __restrict__ out)
{
  int e = blockIdx.z;
  int seg = slot * 8 + e;
  if ((int)(blockIdx.y * 128) >= pcnt[seg]) return;
  __shared__ __align__(16) unsigned short As[128 * GSTR];
  __shared__ __align__(16) unsigned short Ws2[128 * GSTR];
  int t = threadIdx.x;
  int row0 = base[seg] + blockIdx.y * 128;
  int n0 = blockIdx.x * 128;
  int lane = t & 63, w = t >> 6;
  int mw = (w >> 1) * 64, nw = (w & 1) * 64;
  int lr = lane & 15, lg = lane >> 4;

  int srowv[4], sc8v[4];
#pragma unroll
  for (int it = 0; it < 4; it++) { int c = it*256 + t; srowv[it] = c >> 3; sc8v[it] = (c & 7) * 8; }

  uint4 pa[4], pw[4];
  auto ld = [&](int k0) {
#pragma unroll
    for (int it = 0; it < 4; it++) {
      pa[it] = *(const uint4*)(act + (size_t)(row0 + srowv[it]) * NFE + k0 + sc8v[it]);
      pw[it] = *(const uint4*)(Dp + ((size_t)e * ND + n0 + srowv[it]) * NFE + k0 + sc8v[it]);
    }
  };
  auto st = [&]() {
#pragma unroll
    for (int it = 0; it < 4; it++) {
      *(uint4*)&As[srowv[it] * GSTR + sc8v[it]] = pa[it];
      *(uint4*)&Ws2[srowv[it] * GSTR + sc8v[it]] = pw[it];
    }
  };

  f32x4_t acc[4][4];
#pragma unroll
  for (int i = 0; i < 4; i++)
#pragma unroll
    for (int j = 0; j < 4; j++) acc[i][j] = (f32x4_t){0.f, 0.f, 0.f, 0.f};

  ld(0); st();
  __syncthreads();
  for (int k0 = 0; ; ) {
    int kn = k0 + 64;
    if (kn < NFE) ld(kn);
#pragma unroll
    for (int kk = 0; kk < 2; kk++) {
      bf16x8_t af[4], wf[4];
#pragma unroll
      for (int i = 0; i < 4; i++)
        af[i] = *(const bf16x8_t*)&As[(mw + 16*i + lr) * GSTR + kk*32 + lg*8];
#pragma unroll
      for (int j = 0; j < 4; j++)
        wf[j] = *(const bf16x8_t*)&Ws2[(nw + 16*j + lr) * GSTR + kk*32 + lg*8];
#pragma unroll
      for (int i = 0; i < 4; i++)
#pragma unroll
        for (int j = 0; j < 4; j++)
          acc[i][j] = __builtin_amdgcn_mfma_f32_16x16x32_bf16(af[i], wf[j], acc[i][j], 0, 0, 0);
    }
    k0 = kn;
    if (k0 >= NFE) break;
    __syncthreads();
    st();
    __syncthreads();
  }
#pragma unroll
  for (int i = 0; i < 4; i++) {
    int tks[4]; float ews[4];
#pragma unroll
    for (int r = 0; r < 4; r++) {
      int rg = row0 + mw + 16*i + 4*lg + r;
      tks[r] = etok[rg]; ews[r] = ew[rg];
    }
#pragma unroll
    for (int j = 0; j < 4; j++) {
      int n = n0 + nw + 16*j + lr;
#pragma unroll
      for (int r = 0; r < 4; r++) {
        if (tks[r] >= 0)
          out[(size_t)tks[r] * ND + n] += ews[r] * acc[i][j][r];
      }
    }
  }
}

// ===================== launch =====================
extern "C" void kernel_launch(void* const* d_in, const int* in_sizes, int n_in,
                              void* d_out, int out_size, void* d_ws, size_t ws_size,
                              hipStream_t stream) {
  const float* hidden    = (const float*)d_in[0];
  const float* in_ln_w   = (const float*)d_in[2];
  const float* post_ln_w = (const float*)d_in[3];
  const float* wq_a_w    = (const float*)d_in[4];
  const float* wq_a_b    = (const float*)d_in[5];
  const float* q_norm_w  = (const float*)d_in[6];
  const float* wq_b_w    = (const float*)d_in[7];
  const float* wq_b_b    = (const float*)d_in[8];
  const float* wkv_a_w   = (const float*)d_in[9];
  const float* wkv_a_b   = (const float*)d_in[10];
  const float* kv_norm_w = (const float*)d_in[11];
  const float* wkv_b_w   = (const float*)d_in[12];
  const float* wo_w      = (const float*)d_in[13];
  const float* wo_b      = (const float*)d_in[14];
  const float* gate_w    = (const float*)d_in[15];
  const float* gate_b    = (const float*)d_in[16];
  const float* gate_proj = (const float*)d_in[17];
  const float* up_proj   = (const float*)d_in[18];
  const float* down_proj = (const float*)d_in[19];

  float* ws = (float*)d_ws;
  if (ws_size < WS_FLOATS * sizeof(float)) return;

  float* gwp = ws + OFF_GWP;
  float* tkw = ws + OFF_TKW;
  float* ew  = ws + OFF_EW;
  int* ib   = (int*)(ws + OFF_INT);
  int* tke  = ib;
  int* etok = ib + 8192;
  int* cnt  = ib + 8192 + ETOK_CAP;
  int* cnt2 = cnt + 16;
  int* base = cnt + 32;
  int* pcnt = cnt + 48;

  unsigned short* x_bf   = (unsigned short*)(ws + OFF_X);
  unsigned short* oproj  = (unsigned short*)(ws + OFF_X);
  unsigned short* ybuf   = (unsigned short*)(ws + OFF_X);
  float*          qa     = ws + OFF_QA;
  float*          qbuf   = ws + OFF_QA;
  unsigned short* gate_bf= (unsigned short*)(ws + OFF_GATE);
  unsigned short* down_bf= (unsigned short*)(ws + OFF_GATE);
  unsigned short* up_bf  = (unsigned short*)(ws + OFF_UP);
  unsigned short* qab    = (unsigned short*)(ws + OFF_QAB);
  float*          kvp    = ws + OFF_KVP;
  unsigned short* kvc    = (unsigned short*)(ws + OFF_KVC);
  unsigned short* actb   = (unsigned short*)(ws + OFF_ACT);
  unsigned short* wqa_bf = (unsigned short*)(ws + OFF_WA + WA_WQA);
  unsigned short* wqb_bf = (unsigned short*)(ws + OFF_WA + WA_WQB);
  unsigned short* wkva_bf= (unsigned short*)(ws + OFF_WA + WA_WKVA);
  unsigned short* wo_bf  = (unsigned short*)(ws + OFF_WA + WA_WO);

  float* out    = (float*)d_out;
  float* logits = out + (size_t)NTOK * ND;

  // ---- weight conversions (early set)
  conv_bf16_kernel<<<256, 256, 0, stream>>>(wq_a_w, wqa_bf, 524288);
  conv_bf16_kernel<<<144, 256, 0, stream>>>(wkv_a_w, wkva_bf, 294912);
  conv_bf16_kernel<<<384, 256, 0, stream>>>(wq_b_w, wqb_bf, 786432);
  conv_bf16_kernel<<<512, 256, 0, stream>>>(wo_w, wo_bf, 1048576);
  conv_gwp_kernel<<<32, 256, 0, stream>>>(gate_w, post_ln_w, gwp);

  // ---- forward
  rmsnorm_bf16<4><<<NTOK, 256, 0, stream>>>(hidden, ND, in_ln_w, x_bf, ND);
  gemm_bf16<false,false><<<dim3(4, 32), 256, 0, stream>>>(
      x_bf, ND, wqa_bf, ND, wq_a_b, nullptr, qa, 512, 512, ND);
  gemm_bf16<false,false><<<dim3(3, 32), 256, 0, stream>>>(
      x_bf, ND, wkva_bf, ND, wkv_a_b, nullptr, kvp, 288, 288, ND);
  rmsnorm_bf16<2><<<NTOK, 256, 0, stream>>>(qa, 512, q_norm_w, qab, 512);
  // fused kv rmsnorm + rope_k (bit-identical to the two separate kernels)
  rmsnorm_rope_kv<<<NTOK, 256, 0, stream>>>(kvp, kv_norm_w, kvc);
  gemm_bf16<false,false><<<dim3(12, 32), 256, 0, stream>>>(
      qab, 512, wqb_bf, 512, wq_b_b, nullptr, qbuf, 1536, 1536, 512);
  rope_q_kernel<<<4096, 256, 0, stream>>>(qbuf);
  {
    size_t smem = 54528;
    hipFuncSetAttribute((const void*)attn_kernel,
                        hipFuncAttributeMaxDynamicSharedMemorySize, (int)smem);
    attn_kernel<<<dim3(8, NH, NB), 256, smem, stream>>>(qbuf, kvc, wkv_b_w, oproj);
  }
  // qbuf/QAB/KVP/KVC regions dead -> MoE weight conversions
  conv_bf16_kernel<<<4096, 256, 0, stream>>>(gate_proj, gate_bf, 8388608);
  conv_bf16_kernel<<<4096, 256, 0, stream>>>(up_proj, up_bf, 8388608);
  // h = oproj @ wo^T + wo_b + hidden -> d_out (f32)
  gemm_bf16<false,true><<<dim3(8, 32), 256, 0, stream>>>(
      oproj, ND, wo_bf, ND, wo_b, hidden, out, ND, ND, ND);
  // fused post-LN rmsnorm (ybuf) + gate logits
  rms_gate_kernel<<<NTOK, 256, 0, stream>>>(out, post_ln_w, gwp, gate_b, ybuf, logits);
  hipMemsetAsync(cnt, 0, 32 * sizeof(int), stream);
  hipMemsetAsync(etok, 0xFF, ETOK_CAP * sizeof(int), stream);
  topk_kernel<<<16, 256, 0, stream>>>(logits, tke, tkw, cnt);
  offsets_kernel<<<1, 64, 0, stream>>>(cnt, base, pcnt);
  scatter_kernel<<<16, 256, 0, stream>>>(tke, tkw, base, cnt2, etok, ew);
  moe_mlp1_mfma<<<dim3(16, 32, 16), 256, 0, stream>>>(ybuf, gate_bf, up_bf,
                                                      etok, base, pcnt, actb);
  // gate_bf dead -> down_bf conversion
  conv_bf16_kernel<<<4096, 256, 0, stream>>>(down_proj, down_bf, 8388608);
  moe_down_mfma<<<dim3(8, 32, 8), 256, 0, stream>>>(actb, down_bf, etok, ew,
                                                    base, pcnt, 0, out);
  moe_down_mfma<<<dim3(8, 32, 8), 256, 0, stream>>>(actb, down_bf, etok, ew,
                                                    base, pcnt, 1, out);
}

// Round 23
// 895.366 us; speedup vs baseline: 1.0176x; 1.0134x over previous
//
#include <hip/hip_runtime.h>
#include <math.h>

// ===== problem constants =====
#define NB   4
#define NS   1024
#define ND   1024
#define NH   16
#define NTOK 4096
#define NFE  1024
#define ETOK_CAP 10240

// (1/sqrt(96)) * log2(e) — applied to q at attention prologue load; scores in log2 domain
#define SCL_LOG2E 0.14724445f

// ===== workspace layout (f32 slot offsets) =====
static constexpr size_t OFF_GWP  = 0;          // 8,192
static constexpr size_t OFF_TKW  = 8192;       // 8,192
static constexpr size_t OFF_EW   = 16384;      // 10,240 (ends 26,624)
static constexpr size_t OFF_INT  = 26624;      // 18,496 ints = 18,496 slots (ends 45,120)
static constexpr size_t OFF_X    = 45184;      // 2,097,152: x_bf -> oproj -> ybuf (ends 2,142,336)
static constexpr size_t OFF_QA   = 2142336;    // qa f32 2M -> qbuf f32 6,291,456 (ends 8,433,792)
static constexpr size_t OFF_GATE = 2142336;    // gate_bf 4,194,304 (after attn); later down_bf
static constexpr size_t OFF_UP   = 6336640;    // up_bf 4,194,304 (after attn; ends 10,530,944)
static constexpr size_t OFF_QAB  = 8433792;    // qab bf16 1,048,576
static constexpr size_t OFF_KVP  = 9482368;    // kvp f32 1,179,648 (ends 10,662,016)
static constexpr size_t OFF_KVC  = 10662016;   // kvc bf16 589,824 (ends 11,251,840)
static constexpr size_t OFF_WA   = 11251840;   // weight pool 1,327,104 (dead after wo-gemm)
static constexpr size_t WA_WQA   = 0;
static constexpr size_t WA_WQB   = 262144;
static constexpr size_t WA_WKVA  = 655360;
static constexpr size_t WA_WO    = 802816;
static constexpr size_t OFF_ACT  = 10530944;   // actb bf16 5,242,880 (ends 15,773,824)
static constexpr size_t WS_FLOATS = 15773824;

typedef __attribute__((ext_vector_type(8))) short bf16x8_t;
typedef __attribute__((ext_vector_type(4))) float f32x4_t;

__device__ __forceinline__ unsigned pack2(float a, float b) {
  union { float f; unsigned u; } x, y; x.f = a; y.f = b;
  unsigned lo = (x.u + 0x7fffu + ((x.u >> 16) & 1u)) >> 16;
  unsigned hi = (y.u + 0x7fffu + ((y.u >> 16) & 1u)) & 0xffff0000u;
  return (lo & 0xffffu) | hi;
}
__device__ __forceinline__ unsigned short f2bfs(float f) {
  union { float f; unsigned u; } x; x.f = f;
  return (unsigned short)((x.u + 0x7fffu + ((x.u >> 16) & 1u)) >> 16);
}

// ===================== f32 -> bf16 conversion =====================
__global__ __launch_bounds__(256) void conv_bf16_kernel(
    const float* __restrict__ src, unsigned short* __restrict__ dst, int n)
{
  int i = (blockIdx.x * 256 + threadIdx.x) * 8;
  if (i >= n) return;
  float4 a = *(const float4*)(src + i);
  float4 b = *(const float4*)(src + i + 4);
  uint4 o;
  o.x = pack2(a.x, a.y); o.y = pack2(a.z, a.w);
  o.z = pack2(b.x, b.y); o.w = pack2(b.z, b.w);
  *(uint4*)(dst + i) = o;
}

// ===================== merged early weight conversions (wqa|wkva|wqb|wo|gwp) ============
// Block ranges: [0,256) wqa, [256,400) wkva, [400,784) wqb, [784,1296) wo, [1296,1328) gwp.
// Per-element math identical to conv_bf16_kernel / conv_gwp_kernel -> bit-identical.
__global__ __launch_bounds__(256) void conv_weights_kernel(
    const float* __restrict__ wqa, const float* __restrict__ wkva,
    const float* __restrict__ wqb, const float* __restrict__ wo,
    const float* __restrict__ gw,  const float* __restrict__ pw,
    unsigned short* __restrict__ dqa, unsigned short* __restrict__ dkva,
    unsigned short* __restrict__ dqb, unsigned short* __restrict__ dwo,
    float* __restrict__ gwp)
{
  int bid = blockIdx.x;
  if (bid >= 1296) {                    // gwp: gw * pw
    int i = (bid - 1296) * 256 + threadIdx.x;
    gwp[i] = gw[i] * pw[i & 1023];
    return;
  }
  const float* src; unsigned short* dst; int base;
  if (bid < 256)      { src = wqa;  dst = dqa;  base = bid; }
  else if (bid < 400) { src = wkva; dst = dkva; base = bid - 256; }
  else if (bid < 784) { src = wqb;  dst = dqb;  base = bid - 400; }
  else                { src = wo;   dst = dwo;  base = bid - 784; }
  int i = (base * 256 + threadIdx.x) * 8;
  float4 a = *(const float4*)(src + i);
  float4 b = *(const float4*)(src + i + 4);
  uint4 o;
  o.x = pack2(a.x, a.y); o.y = pack2(a.z, a.w);
  o.z = pack2(b.x, b.y); o.w = pack2(b.z, b.w);
  *(uint4*)(dst + i) = o;
}

// ===================== merged gate/up conversion (2 x 4096 blocks) ======================
__global__ __launch_bounds__(256) void conv_gu_kernel(
    const float* __restrict__ g, const float* __restrict__ u,
    unsigned short* __restrict__ dg, unsigned short* __restrict__ du)
{
  int bid = blockIdx.x;
  const float* src = (bid < 4096) ? g : u;
  unsigned short* dst = (bid < 4096) ? dg : du;
  int base = (bid < 4096) ? bid : bid - 4096;
  int i = (base * 256 + threadIdx.x) * 8;
  float4 a = *(const float4*)(src + i);
  float4 b = *(const float4*)(src + i + 4);
  uint4 o;
  o.x = pack2(a.x, a.y); o.y = pack2(a.z, a.w);
  o.z = pack2(b.x, b.y); o.w = pack2(b.z, b.w);
  *(uint4*)(dst + i) = o;
}

// ===================== RMSNorm (f32 in -> bf16 out) =====================
template<int PER>
__global__ __launch_bounds__(256) void rmsnorm_bf16(
    const float* in, int istr, const float* w, unsigned short* out, int ostr)
{
  int row = blockIdx.x, t = threadIdx.x;
  const float* ip = in + (size_t)row * istr;
  float v[PER];
  float ss = 0.f;
#pragma unroll
  for (int i = 0; i < PER; i++) { v[i] = ip[t + i*256]; ss += v[i]*v[i]; }
#pragma unroll
  for (int k = 1; k < 64; k <<= 1) ss += __shfl_xor(ss, k);
  __shared__ float red[4];
  if ((t & 63) == 0) red[t >> 6] = ss;
  __syncthreads();
  float tot = red[0] + red[1] + red[2] + red[3];
  float inv = rsqrtf(tot * (1.f / (PER * 256)) + 1e-6f);
  unsigned short* op = out + (size_t)row * ostr;
#pragma unroll
  for (int i = 0; i < PER; i++) op[t + i*256] = f2bfs(v[i] * inv * w[t + i*256]);
}

// ===================== fused kv rmsnorm (cols 0..255) + rope_k (cols 256..287) ==========
// Arithmetic verbatim from rmsnorm_bf16<1> and rope_k_kernel -> bit-identical kvc.
__global__ __launch_bounds__(256) void rmsnorm_rope_kv(
    const float* __restrict__ kvp, const float* __restrict__ w,
    unsigned short* __restrict__ kvc)
{
  int row = blockIdx.x, t = threadIdx.x;
  const float* ip = kvp + (size_t)row * 288;
  float v = ip[t];
  float ss = v * v;
#pragma unroll
  for (int k = 1; k < 64; k <<= 1) ss += __shfl_xor(ss, k);
  __shared__ float red[4];
  if ((t & 63) == 0) red[t >> 6] = ss;
  __syncthreads();
  float tot = red[0] + red[1] + red[2] + red[3];
  float inv = rsqrtf(tot * (1.f / 256.f) + 1e-6f);
  unsigned short* op = kvc + (size_t)row * 288;
  op[t] = f2bfs(v * inv * w[t]);
  if (t < 16) {
    int s = row & (NS - 1);
    float invf = __expf(-(float)(2 * t) * (9.210340371976184f / 32.f));
    float fr = (float)s * invf;
    float sn, cs; sincosf(fr, &sn, &cs);
    float x1 = ip[256 + t], x2 = ip[256 + t + 16];
    op[256 + t]      = f2bfs(x1 * cs - x2 * sn);
    op[256 + t + 16] = f2bfs(x2 * cs + x1 * sn);
  }
}

// ===================== fused post-LN rmsnorm + gate logits =====================
__global__ __launch_bounds__(256) void rms_gate_kernel(
    const float* __restrict__ H, const float* __restrict__ pw,
    const float* __restrict__ gwp, const float* __restrict__ gb,
    unsigned short* __restrict__ ybuf, float* __restrict__ logits)
{
  __shared__ __align__(16) float ly[1024];
  __shared__ float red[4];
  int tok = blockIdx.x, t = threadIdx.x;
  float4 hv = *(const float4*)(H + (size_t)tok * ND + t * 4);
  *(float4*)&ly[t * 4] = hv;
  float ss = hv.x*hv.x + hv.y*hv.y + hv.z*hv.z + hv.w*hv.w;
#pragma unroll
  for (int k = 1; k < 64; k <<= 1) ss += __shfl_xor(ss, k);
  if ((t & 63) == 0) red[t >> 6] = ss;
  __syncthreads();
  float inv = rsqrtf((red[0] + red[1] + red[2] + red[3]) * (1.f / 1024.f) + 1e-6f);
  float4 pw4 = *(const float4*)(pw + t * 4);
  unsigned short* yb = ybuf + (size_t)tok * ND + t * 4;
  yb[0] = f2bfs((hv.x * inv) * pw4.x);
  yb[1] = f2bfs((hv.y * inv) * pw4.y);
  yb[2] = f2bfs((hv.z * inv) * pw4.z);
  yb[3] = f2bfs((hv.w * inv) * pw4.w);
  int e = t >> 5, lane = t & 31;
  const float* w = gwp + (size_t)e * ND;
  float acc = 0.f;
  for (int d = lane; d < ND; d += 32) acc += ly[d] * w[d];
#pragma unroll
  for (int k = 16; k >= 1; k >>= 1) acc += __shfl_xor(acc, k);
  if (lane == 0) logits[(size_t)tok * 8 + e] = acc * inv + gb[e];
}

// ===================== bf16 MFMA GEMM: C = A @ W^T + bias (+resid) (+fused rope_q) ======
// ROPE=true (qbuf GEMM only): the pe pair (cols h*96+64+d, h*96+80+d) always lands in
// adjacent j-blocks of the SAME wave (jp in {0,2}); rotation applied to v=acc+bias with
// rope_q's exact formulas (d=lr, s=m&1023) -> bit-identical to separate rope_q pass.
#define GSTR 72

template<bool OUTBF, bool RESID, bool ROPE = false>
__global__ __launch_bounds__(256) void gemm_bf16(
    const unsigned short* __restrict__ A, int lda,
    const unsigned short* __restrict__ W, int ldw,
    const float* __restrict__ bias,
    const float* __restrict__ resid,
    void* __restrict__ Cv, int ldc, int N, int K)
{
  __shared__ __align__(16) unsigned short As[128 * GSTR];
  __shared__ __align__(16) unsigned short Ws2[128 * GSTR];
  int t = threadIdx.x;
  int m0 = blockIdx.y * 128, n0 = blockIdx.x * 128;
  int lane = t & 63, w = t >> 6;
  int mw = (w >> 1) * 64, nw = (w & 1) * 64;
  int lr = lane & 15, lg = lane >> 4;

  int srowv[4], sc8v[4];
#pragma unroll
  for (int it = 0; it < 4; it++) { int c = it*256 + t; srowv[it] = c >> 3; sc8v[it] = (c & 7) * 8; }

  uint4 pa[4], pw[4];
  auto ld = [&](int k0) {
#pragma unroll
    for (int it = 0; it < 4; it++) {
      pa[it] = *(const uint4*)(A + (size_t)(m0 + srowv[it]) * lda + k0 + sc8v[it]);
      int r = n0 + srowv[it];
      pw[it] = (r < N) ? *(const uint4*)(W + (size_t)r * ldw + k0 + sc8v[it])
                       : make_uint4(0u, 0u, 0u, 0u);
    }
  };
  auto st = [&]() {
#pragma unroll
    for (int it = 0; it < 4; it++) {
      *(uint4*)&As[srowv[it] * GSTR + sc8v[it]] = pa[it];
      *(uint4*)&Ws2[srowv[it] * GSTR + sc8v[it]] = pw[it];
    }
  };

  f32x4_t acc[4][4];
#pragma unroll
  for (int i = 0; i < 4; i++)
#pragma unroll
    for (int j = 0; j < 4; j++) acc[i][j] = (f32x4_t){0.f, 0.f, 0.f, 0.f};

  ld(0); st();
  __syncthreads();
  for (int k0 = 0; ; ) {
    int kn = k0 + 64;
    if (kn < K) ld(kn);
#pragma unroll
    for (int kk = 0; kk < 2; kk++) {
      bf16x8_t af[4], wf[4];
#pragma unroll
      for (int i = 0; i < 4; i++)
        af[i] = *(const bf16x8_t*)&As[(mw + 16*i + lr) * GSTR + kk*32 + lg*8];
#pragma unroll
      for (int j = 0; j < 4; j++)
        wf[j] = *(const bf16x8_t*)&Ws2[(nw + 16*j + lr) * GSTR + kk*32 + lg*8];
#pragma unroll
      for (int i = 0; i < 4; i++)
#pragma unroll
        for (int j = 0; j < 4; j++)
          acc[i][j] = __builtin_amdgcn_mfma_f32_16x16x32_bf16(af[i], wf[j], acc[i][j], 0, 0, 0);
    }
    k0 = kn;
    if (k0 >= K) break;
    __syncthreads();
    st();
    __syncthreads();
  }
  float bvs[4];
#pragma unroll
  for (int j = 0; j < 4; j++) {
    int n = n0 + nw + 16*j + lr;
    bvs[j] = (n < N) ? bias[n] : 0.f;
  }
  if (ROPE) {
#pragma unroll
    for (int jp = 0; jp < 3; jp++) {
      int nb = n0 + nw + 16*jp;
      if (nb % 96 == 64) {               // pe-low block; pair with jp+1 (wave-uniform)
        float invf = __expf(-(float)(2 * lr) * (9.210340371976184f / 32.f));
#pragma unroll
        for (int i = 0; i < 4; i++) {
#pragma unroll
          for (int r = 0; r < 4; r++) {
            int m = m0 + mw + 16*i + 4*lg + r;
            int s = m & (NS - 1);
            float fr = (float)s * invf;
            float sn, cs; sincosf(fr, &sn, &cs);
            float x1 = acc[i][jp][r] + bvs[jp];
            float x2 = acc[i][jp+1][r] + bvs[jp+1];
            acc[i][jp][r]   = x1 * cs - x2 * sn;
            acc[i][jp+1][r] = x2 * cs + x1 * sn;
          }
        }
        bvs[jp] = 0.f; bvs[jp+1] = 0.f;   // bias already applied in rotation
      }
    }
  }
#pragma unroll
  for (int j = 0; j < 4; j++) {
    int n = n0 + nw + 16*j + lr;
    if (n < N) {
      float bv = bvs[j];
#pragma unroll
      for (int i = 0; i < 4; i++) {
#pragma unroll
        for (int r = 0; r < 4; r++) {
          int m = m0 + mw + 16*i + 4*lg + r;
          size_t off = (size_t)m * ldc + n;
          float v = acc[i][j][r] + bv;
          if (RESID) v += resid[off];
          if (OUTBF) ((unsigned short*)Cv)[off] = f2bfs(v);
          else       ((float*)Cv)[off] = v;
        }
      }
    }
  }
}

// ===================== MLA flash attention v8 — EXACT R12/R14/R17 kernel =====================
// Paired q-tiles {15-bx, bx} per block -> uniform 34 tiles/block; grid 512 = 2 blocks/CU.
// V staged by per-feature gather; exact f32 prologue/epilogue. dynamic LDS 54,528 B.
#define KSTR 296
#define QNSTR 65
#define VPAD 40
#define OSTR2 132

__global__ __launch_bounds__(256, 2) void attn_kernel(
    const float* __restrict__ qbuf,           // (NTOK,1536) f32 post-rope
    const unsigned short* __restrict__ kvc,   // (NTOK,288) bf16
    const float* __restrict__ wkvb,           // (H*128,256) f32
    unsigned short* __restrict__ oproj)       // (NTOK,1024) bf16
{
  extern __shared__ float4 smem_f4[];
  unsigned short* sm  = (unsigned short*)smem_f4;
  unsigned short* ks  = sm;             // [32][KSTR] loop
  unsigned short* vt  = sm + 9472;      // [256][VPAD] loop
  unsigned short* ps  = sm + 19712;     // [64][32] loop
  float* qn           = (float*)sm;     // [64][QNSTR] prologue
  unsigned short* qst = sm + 8320;      // [64][KSTR] prologue
  float* o_lds        = (float*)sm;     // [64][OSTR2] epilogue

  int bx = blockIdx.x;                  // 0..7
  int h = blockIdx.y, b = blockIdx.z;
  int t = threadIdx.x;
  int lane = t & 63, wv_ = t >> 6;
  int lrow = lane & 15, lg = lane >> 4;
  int qrow = 16 * wv_ + lrow;

  int srow[5], sc16[5];
#pragma unroll
  for (int it = 0; it < 5; it++) {
    int c = it * 256 + t;
    srow[it] = c / 36; sc16[it] = c % 36;
  }
  bool tail = (t < 128);

  for (int half = 0; half < 2; half++) {
    int qb = half ? bx : (15 - bx);     // heavy tile first
    int row0 = b * NS + qb * 64;
    __syncthreads();                    // previous half's LDS fully consumed

    // ---- prologue a: q_nope (f32, scaled) -> qn ; q_pe -> bq[8]
    for (int idx = t; idx < 4096; idx += 256) {
      int r = idx >> 6, c = idx & 63;
      qn[r * QNSTR + c] = qbuf[(size_t)(row0 + r) * 1536 + h * 96 + c] * SCL_LOG2E;
    }
    bf16x8_t bq[9];
    {
      const float* src = qbuf + (size_t)(row0 + qrow) * 1536 + h * 96 + 64 + lg * 8;
      unsigned short* bp = (unsigned short*)&bq[8];
#pragma unroll
      for (int j = 0; j < 8; j++) bp[j] = f2bfs(src[j] * SCL_LOG2E);
    }
    __syncthreads();
    // ---- prologue b: q_abs = q_nope @ wkv_b[h,0:64,:]  (f32 VALU, exact)
    {
      int cx = t & 63, ry = t >> 6;
      float a[16][4] = {};
      const float* wb = wkvb + (size_t)h * 32768 + cx * 4;
      for (int k = 0; k < 64; k++) {
        float4 wv = *(const float4*)(wb + (size_t)k * 256);
#pragma unroll
        for (int r = 0; r < 16; r++) {
          float qv = qn[(ry * 16 + r) * QNSTR + k];
          a[r][0] += qv * wv.x; a[r][1] += qv * wv.y; a[r][2] += qv * wv.z; a[r][3] += qv * wv.w;
        }
      }
      __syncthreads();   // qn reads done before qst (overlapping region) is written
#pragma unroll
      for (int r = 0; r < 16; r++) {
        uint2 pk; pk.x = pack2(a[r][0], a[r][1]); pk.y = pack2(a[r][2], a[r][3]);
        *(uint2*)&qst[(ry * 16 + r) * KSTR + cx * 4] = pk;
      }
    }
    __syncthreads();
#pragma unroll
    for (int kk = 0; kk < 8; kk++)
      bq[kk] = *(const bf16x8_t*)&qst[qrow * KSTR + kk * 32 + lg * 8];
    __syncthreads();

    // ---- loop state
    float m_run = -1e30f, l_run = 0.f;
    f32x4_t acco[16];
#pragma unroll
    for (int n = 0; n < 16; n++) acco[n] = (f32x4_t){0.f, 0.f, 0.f, 0.f};

    uint4 pa[5];
    unsigned short vg[32];

    auto issue = [&](int kb2) {
      const unsigned short* tb = kvc + ((size_t)b * NS + kb2 * 32) * 288;
#pragma unroll
      for (int it = 0; it < 4; it++)
        pa[it] = *(const uint4*)(tb + srow[it] * 288 + sc16[it] * 8);
      if (tail) pa[4] = *(const uint4*)(tb + srow[4] * 288 + sc16[4] * 8);
      const unsigned short* vsrc = tb + t;   // feature t, keys 0..31
#pragma unroll
      for (int k = 0; k < 32; k++) vg[k] = vsrc[k * 288];
    };
    auto commit = [&]() {
#pragma unroll
      for (int it = 0; it < 5; it++) {
        if (it == 4 && !tail) continue;
        *(uint4*)&ks[srow[it] * KSTR + sc16[it] * 8] = pa[it];
      }
      unsigned wds[16];
#pragma unroll
      for (int j = 0; j < 16; j++)
        wds[j] = (unsigned)vg[2*j] | ((unsigned)vg[2*j+1] << 16);
#pragma unroll
      for (int j = 0; j < 4; j++)
        *(uint4*)&vt[t * VPAD + j * 8] =
          make_uint4(wds[4*j], wds[4*j+1], wds[4*j+2], wds[4*j+3]);
    };

    int nkb = 2 * qb + 2;
    issue(0); commit();
    __syncthreads();
    for (int kb = 0; kb < nkb; kb++) {
      bool more = (kb + 1 < nkb);
      if (more) issue(kb + 1);
      int key0 = kb * 32;
      // ---- scores (even/odd chains), K-dim 288
      f32x4_t s0e = {0.f,0.f,0.f,0.f}, s0o = {0.f,0.f,0.f,0.f};
      f32x4_t s1e = {0.f,0.f,0.f,0.f}, s1o = {0.f,0.f,0.f,0.f};
#pragma unroll
      for (int kk = 0; kk < 9; kk++) {
        bf16x8_t a0 = *(const bf16x8_t*)&ks[lrow * KSTR + kk*32 + lg*8];
        bf16x8_t a1 = *(const bf16x8_t*)&ks[(16 + lrow) * KSTR + kk*32 + lg*8];
        if (kk & 1) {
          s0o = __builtin_amdgcn_mfma_f32_16x16x32_bf16(a0, bq[kk], s0o, 0, 0, 0);
          s1o = __builtin_amdgcn_mfma_f32_16x16x32_bf16(a1, bq[kk], s1o, 0, 0, 0);
        } else {
          s0e = __builtin_amdgcn_mfma_f32_16x16x32_bf16(a0, bq[kk], s0e, 0, 0, 0);
          s1e = __builtin_amdgcn_mfma_f32_16x16x32_bf16(a1, bq[kk], s1e, 0, 0, 0);
        }
      }
      f32x4_t s0a = s0e + s0o, s1a = s1e + s1o;
      // ---- causal mask (skipped on full tiles) + online softmax in log2 domain
      int qg = qb * 64 + qrow;
      float sv[8];
      if (key0 + 31 > qb * 64 + 16 * wv_) {
#pragma unroll
        for (int r = 0; r < 4; r++) {
          sv[r]     = (key0 + 4*lg + r      <= qg) ? s0a[r] : -1e30f;
          sv[4 + r] = (key0 + 16 + 4*lg + r <= qg) ? s1a[r] : -1e30f;
        }
      } else {
#pragma unroll
        for (int r = 0; r < 4; r++) { sv[r] = s0a[r]; sv[4 + r] = s1a[r]; }
      }
      float mx = sv[0];
#pragma unroll
      for (int i = 1; i < 8; i++) mx = fmaxf(mx, sv[i]);
      mx = fmaxf(mx, __shfl_xor(mx, 16));
      mx = fmaxf(mx, __shfl_xor(mx, 32));
      if (!__all(mx - m_run <= 11.0f)) {   // defer-max (T13)
        float mnew = fmaxf(m_run, mx);
        float al = exp2f(m_run - mnew);
        m_run = mnew;
        l_run *= al;
        float al0 = __shfl(al, 4*lg + 0);
        float al1 = __shfl(al, 4*lg + 1);
        float al2 = __shfl(al, 4*lg + 2);
        float al3 = __shfl(al, 4*lg + 3);
#pragma unroll
        for (int n = 0; n < 16; n++) {
          acco[n][0] *= al0; acco[n][1] *= al1; acco[n][2] *= al2; acco[n][3] *= al3;
        }
      }
      float sum = 0.f;
#pragma unroll
      for (int i = 0; i < 8; i++) { sv[i] = exp2f(sv[i] - m_run); sum += sv[i]; }
      sum += __shfl_xor(sum, 16);
      sum += __shfl_xor(sum, 32);
      l_run += sum;
      // ---- P -> ps (bf16, XOR-swizzled 16B granules)
      {
        int swz = qrow & 3;
        int g0 = lg >> 1, h0 = lg & 1;
        uint2 p0; p0.x = pack2(sv[0], sv[1]); p0.y = pack2(sv[2], sv[3]);
        uint2 p1; p1.x = pack2(sv[4], sv[5]); p1.y = pack2(sv[6], sv[7]);
        char* pr = (char*)ps + qrow * 64;
        *(uint2*)(pr + ((g0 ^ swz) * 16 + h0 * 8))       = p0;
        *(uint2*)(pr + (((2 + g0) ^ swz) * 16 + h0 * 8)) = p1;
      }
      // ---- PV (vt rows feature-major; row start banks tile all 32 banks)
      {
        bf16x8_t ap = *(const bf16x8_t*)((char*)ps + qrow * 64 + ((lg ^ (qrow & 3)) * 16));
#pragma unroll
        for (int n = 0; n < 16; n++) {
          bf16x8_t bv = *(const bf16x8_t*)&vt[(16*n + lrow) * VPAD + lg * 8];
          acco[n] = __builtin_amdgcn_mfma_f32_16x16x32_bf16(ap, bv, acco[n], 0, 0, 0);
        }
      }
      __syncthreads();
      if (more) { commit(); __syncthreads(); }
    }
    // ---- epilogue: normalize; 2-pass f32 o_lds; o @ wkv_b[h,64:,:]^T (f32 VALU, exact)
    float li = 1.f / l_run;
    float l0 = __shfl(li, 4*lg + 0);
    float l1 = __shfl(li, 4*lg + 1);
    float l2 = __shfl(li, 4*lg + 2);
    float l3 = __shfl(li, 4*lg + 3);
    int dx = t & 15, ty2 = t >> 4;
    float pr[4][4] = {};
    const float* wb2 = wkvb + (size_t)(h * 128 + 64) * 256;
#pragma unroll
    for (int p = 0; p < 2; p++) {
      __syncthreads();
#pragma unroll
      for (int n = 8*p; n < 8*p + 8; n++) {
        int fc = 16*n + lrow - 128*p;
        o_lds[(16*wv_ + 4*lg + 0) * OSTR2 + fc] = acco[n][0] * l0;
        o_lds[(16*wv_ + 4*lg + 1) * OSTR2 + fc] = acco[n][1] * l1;
        o_lds[(16*wv_ + 4*lg + 2) * OSTR2 + fc] = acco[n][2] * l2;
        o_lds[(16*wv_ + 4*lg + 3) * OSTR2 + fc] = acco[n][3] * l3;
      }
      __syncthreads();
      for (int c = 0; c < 128; c += 4) {
        float4 w0 = *(const float4*)(wb2 + (size_t)(dx*4 + 0) * 256 + 128*p + c);
        float4 w1 = *(const float4*)(wb2 + (size_t)(dx*4 + 1) * 256 + 128*p + c);
        float4 w2 = *(const float4*)(wb2 + (size_t)(dx*4 + 2) * 256 + 128*p + c);
        float4 w3 = *(const float4*)(wb2 + (size_t)(dx*4 + 3) * 256 + 128*p + c);
#pragma unroll
        for (int i = 0; i < 4; i++) {
          float4 ov = *(const float4*)&o_lds[(ty2*4 + i) * OSTR2 + c];
          pr[i][0] += ov.x*w0.x + ov.y*w0.y + ov.z*w0.z + ov.w*w0.w;
          pr[i][1] += ov.x*w1.x + ov.y*w1.y + ov.z*w1.z + ov.w*w1.w;
          pr[i][2] += ov.x*w2.x + ov.y*w2.y + ov.z*w2.z + ov.w*w2.w;
          pr[i][3] += ov.x*w3.x + ov.y*w3.y + ov.z*w3.z + ov.w*w3.w;
        }
      }
    }
#pragma unroll
    for (int i = 0; i < 4; i++)
#pragma unroll
      for (int j = 0; j < 4; j++)
        oproj[(size_t)(row0 + ty2*4 + i) * 1024 + h * 64 + dx*4 + j] = f2bfs(pr[i][j]);
  }
}

// ===================== top-2 gating + counts =====================
__global__ __launch_bounds__(256) void topk_kernel(
    const float* __restrict__ logits, int* __restrict__ tke,
    float* __restrict__ tkw, int* __restrict__ cnt)
{
  int tok = blockIdx.x * 256 + threadIdx.x;
  if (tok >= NTOK) return;
  float l[8];
#pragma unroll
  for (int e2 = 0; e2 < 8; e2++) l[e2] = logits[(size_t)tok * 8 + e2];
  float v0 = l[0]; int e0 = 0;
#pragma unroll
  for (int e2 = 1; e2 < 8; e2++) if (l[e2] > v0) { v0 = l[e2]; e0 = e2; }
  float v1 = -INFINITY; int e1 = 0;
#pragma unroll
  for (int e2 = 0; e2 < 8; e2++) if (e2 != e0 && l[e2] > v1) { v1 = l[e2]; e1 = e2; }
  float x = __expf(v1 - v0);
  float w0 = 1.f / (1.f + x);
  tke[tok * 2]     = e0; tke[tok * 2 + 1] = e1;
  tkw[tok * 2]     = w0; tkw[tok * 2 + 1] = 1.f - w0;
  atomicAdd(&cnt[e0], 1);
  atomicAdd(&cnt[8 + e1], 1);
}

__global__ void offsets_kernel(const int* cnt, int* base, int* pcnt)
{
  if (threadIdx.x == 0 && blockIdx.x == 0) {
    int cum = 0;
    for (int s2 = 0; s2 < 16; s2++) {
      int p = (cnt[s2] + 127) & ~127;
      base[s2] = cum; pcnt[s2] = p; cum += p;
    }
  }
}

__global__ __launch_bounds__(256) void scatter_kernel(
    const int* __restrict__ tke, const float* __restrict__ tkw,
    const int* __restrict__ base, int* cnt2,
    int* __restrict__ etok, float* __restrict__ ew)
{
  int tok = blockIdx.x * 256 + threadIdx.x;
  if (tok >= NTOK) return;
#pragma unroll
  for (int k = 0; k < 2; k++) {
    int e = tke[tok * 2 + k];
    int seg = k * 8 + e;
    int pos = atomicAdd(&cnt2[seg], 1);
    int row = base[seg] + pos;
    etok[row] = tok;
    ew[row] = tkw[tok * 2 + k];
  }
}

// ===================== MoE mlp1 v2 (all bf16): 128x64 tile, BK=64, 4 waves (2m x 2n) =======
__global__ __launch_bounds__(256, 3) void moe_mlp1_mfma(
    const unsigned short* __restrict__ Y,
    const unsigned short* __restrict__ Gp, const unsigned short* __restrict__ Up,
    const int* __restrict__ etok, const int* __restrict__ base,
    const int* __restrict__ pcnt, unsigned short* __restrict__ act)
{
  int seg = blockIdx.z;
  if ((int)(blockIdx.y * 128) >= pcnt[seg]) return;
  int e = seg & 7;
  __shared__ __align__(16) unsigned short As[128 * GSTR];
  __shared__ __align__(16) unsigned short Gs[64 * GSTR];
  __shared__ __align__(16) unsigned short Us[64 * GSTR];
  int t = threadIdx.x;
  int row0 = base[seg] + blockIdx.y * 128;
  int n0 = blockIdx.x * 64;
  int lane = t & 63, w = t >> 6;
  int mw = (w >> 1) * 64, nw = (w & 1) * 32;
  int lr = lane & 15, lg = lane >> 4;

  int srow = t >> 3, sc8 = (t & 7) * 8;
  int tokr[4];
#pragma unroll
  for (int it = 0; it < 4; it++) tokr[it] = etok[row0 + it*32 + srow];

  uint4 pa[4], pg[2], pu[2];
  auto ld = [&](int k0) {
#pragma unroll
    for (int it = 0; it < 4; it++)
      pa[it] = (tokr[it] >= 0)
        ? *(const uint4*)(Y + (size_t)tokr[it] * ND + k0 + sc8)
        : make_uint4(0u, 0u, 0u, 0u);
#pragma unroll
    for (int it = 0; it < 2; it++) {
      int r = n0 + it*32 + srow;
      pg[it] = *(const uint4*)(Gp + ((size_t)e * NFE + r) * ND + k0 + sc8);
      pu[it] = *(const uint4*)(Up + ((size_t)e * NFE + r) * ND + k0 + sc8);
    }
  };
  auto st = [&]() {
#pragma unroll
    for (int it = 0; it < 4; it++)
      *(uint4*)&As[(it*32 + srow) * GSTR + sc8] = pa[it];
#pragma unroll
    for (int it = 0; it < 2; it++) {
      *(uint4*)&Gs[(it*32 + srow) * GSTR + sc8] = pg[it];
      *(uint4*)&Us[(it*32 + srow) * GSTR + sc8] = pu[it];
    }
  };

  f32x4_t accg[4][2], accu[4][2];
#pragma unroll
  for (int i = 0; i < 4; i++)
#pragma unroll
    for (int j = 0; j < 2; j++) {
      accg[i][j] = (f32x4_t){0.f, 0.f, 0.f, 0.f};
      accu[i][j] = (f32x4_t){0.f, 0.f, 0.f, 0.f};
    }

  ld(0); st();
  __syncthreads();
  for (int k0 = 0; ; ) {
    int kn = k0 + 64;
    if (kn < ND) ld(kn);
#pragma unroll
    for (int kk = 0; kk < 2; kk++) {
      bf16x8_t af[4], gf[2], uf[2];
#pragma unroll
      for (int i = 0; i < 4; i++)
        af[i] = *(const bf16x8_t*)&As[(mw + 16*i + lr) * GSTR + kk*32 + lg*8];
#pragma unroll
      for (int j = 0; j < 2; j++) {
        gf[j] = *(const bf16x8_t*)&Gs[(nw + 16*j + lr) * GSTR + kk*32 + lg*8];
        uf[j] = *(const bf16x8_t*)&Us[(nw + 16*j + lr) * GSTR + kk*32 + lg*8];
      }
#pragma unroll
      for (int i = 0; i < 4; i++)
#pragma unroll
        for (int j = 0; j < 2; j++) {
          accg[i][j] = __builtin_amdgcn_mfma_f32_16x16x32_bf16(af[i], gf[j], accg[i][j], 0, 0, 0);
          accu[i][j] = __builtin_amdgcn_mfma_f32_16x16x32_bf16(af[i], uf[j], accu[i][j], 0, 0, 0);
        }
    }
    k0 = kn;
    if (k0 >= ND) break;
    __syncthreads();
    st();
    __syncthreads();
  }
#pragma unroll
  for (int i = 0; i < 4; i++)
#pragma unroll
    for (int j = 0; j < 2; j++) {
      int n = n0 + nw + 16*j + lr;
#pragma unroll
      for (int r = 0; r < 4; r++) {
        int m = row0 + mw + 16*i + 4*lg + r;
        float g = accg[i][j][r], u = accu[i][j][r];
        float s = g / (1.f + __expf(-g));
        act[(size_t)m * NFE + n] = f2bfs(s * u);
      }
    }
}

// ===================== MoE down v1 (all bf16): 128x128 tile, BK=64 =====================
__global__ __launch_bounds__(256) void moe_down_mfma(
    const unsigned short* __restrict__ act, const unsigned short* __restrict__ Dp,
    const int* __restrict__ etok, const float* __restrict__ ew,
    const int* __restrict__ base, const int* __restrict__ pcnt,
    int slot, float* __restrict__ out)
{
  int e = blockIdx.z;
  int seg = slot * 8 + e;
  if ((int)(blockIdx.y * 128) >= pcnt[seg]) return;
  __shared__ __align__(16) unsigned short As[128 * GSTR];
  __shared__ __align__(16) unsigned short Ws2[128 * GSTR];
  int t = threadIdx.x;
  int row0 = base[seg] + blockIdx.y * 128;
  int n0 = blockIdx.x * 128;
  int lane = t & 63, w = t >> 6;
  int mw = (w >> 1) * 64, nw = (w & 1) * 64;
  int lr = lane & 15, lg = lane >> 4;

  int srowv[4], sc8v[4];
#pragma unroll
  for (int it = 0; it < 4; it++) { int c = it*256 + t; srowv[it] = c >> 3; sc8v[it] = (c & 7) * 8; }

  uint4 pa[4], pw[4];
  auto ld = [&](int k0) {
#pragma unroll
    for (int it = 0; it < 4; it++) {
      pa[it] = *(const uint4*)(act + (size_t)(row0 + srowv[it]) * NFE + k0 + sc8v[it]);
      pw[it] = *(const uint4*)(Dp + ((size_t)e * ND + n0 + srowv[it]) * NFE + k0 + sc8v[it]);
    }
  };
  auto st = [&]() {
#pragma unroll
    for (int it = 0; it < 4; it++) {
      *(uint4*)&As[srowv[it] * GSTR + sc8v[it]] = pa[it];
      *(uint4*)&Ws2[srowv[it] * GSTR + sc8v[it]] = pw[it];
    }
  };

  f32x4_t acc[4][4];
#pragma unroll
  for (int i = 0; i < 4; i++)
#pragma unroll
    for (int j = 0; j < 4; j++) acc[i][j] = (f32x4_t){0.f, 0.f, 0.f, 0.f};

  ld(0); st();
  __syncthreads();
  for (int k0 = 0; ; ) {
    int kn = k0 + 64;
    if (kn < NFE) ld(kn);
#pragma unroll
    for (int kk = 0; kk < 2; kk++) {
      bf16x8_t af[4], wf[4];
#pragma unroll
      for (int i = 0; i < 4; i++)
        af[i] = *(const bf16x8_t*)&As[(mw + 16*i + lr) * GSTR + kk*32 + lg*8];
#pragma unroll
      for (int j = 0; j < 4; j++)
        wf[j] = *(const bf16x8_t*)&Ws2[(nw + 16*j + lr) * GSTR + kk*32 + lg*8];
#pragma unroll
      for (int i = 0; i < 4; i++)
#pragma unroll
        for (int j = 0; j < 4; j++)
          acc[i][j] = __builtin_amdgcn_mfma_f32_16x16x32_bf16(af[i], wf[j], acc[i][j], 0, 0, 0);
    }
    k0 = kn;
    if (k0 >= NFE) break;
    __syncthreads();
    st();
    __syncthreads();
  }
#pragma unroll
  for (int i = 0; i < 4; i++) {
    int tks[4]; float ews[4];
#pragma unroll
    for (int r = 0; r < 4; r++) {
      int rg = row0 + mw + 16*i + 4*lg + r;
      tks[r] = etok[rg]; ews[r] = ew[rg];
    }
#pragma unroll
    for (int j = 0; j < 4; j++) {
      int n = n0 + nw + 16*j + lr;
#pragma unroll
      for (int r = 0; r < 4; r++) {
        if (tks[r] >= 0)
          out[(size_t)tks[r] * ND + n] += ews[r] * acc[i][j][r];
      }
    }
  }
}

// ===================== launch =====================
extern "C" void kernel_launch(void* const* d_in, const int* in_sizes, int n_in,
                              void* d_out, int out_size, void* d_ws, size_t ws_size,
                              hipStream_t stream) {
  const float* hidden    = (const float*)d_in[0];
  const float* in_ln_w   = (const float*)d_in[2];
  const float* post_ln_w = (const float*)d_in[3];
  const float* wq_a_w    = (const float*)d_in[4];
  const float* wq_a_b    = (const float*)d_in[5];
  const float* q_norm_w  = (const float*)d_in[6];
  const float* wq_b_w    = (const float*)d_in[7];
  const float* wq_b_b    = (const float*)d_in[8];
  const float* wkv_a_w   = (const float*)d_in[9];
  const float* wkv_a_b   = (const float*)d_in[10];
  const float* kv_norm_w = (const float*)d_in[11];
  const float* wkv_b_w   = (const float*)d_in[12];
  const float* wo_w      = (const float*)d_in[13];
  const float* wo_b      = (const float*)d_in[14];
  const float* gate_w    = (const float*)d_in[15];
  const float* gate_b    = (const float*)d_in[16];
  const float* gate_proj = (const float*)d_in[17];
  const float* up_proj   = (const float*)d_in[18];
  const float* down_proj = (const float*)d_in[19];

  float* ws = (float*)d_ws;
  if (ws_size < WS_FLOATS * sizeof(float)) return;

  float* gwp = ws + OFF_GWP;
  float* tkw = ws + OFF_TKW;
  float* ew  = ws + OFF_EW;
  int* ib   = (int*)(ws + OFF_INT);
  int* tke  = ib;
  int* etok = ib + 8192;
  int* cnt  = ib + 8192 + ETOK_CAP;
  int* cnt2 = cnt + 16;
  int* base = cnt + 32;
  int* pcnt = cnt + 48;

  unsigned short* x_bf   = (unsigned short*)(ws + OFF_X);
  unsigned short* oproj  = (unsigned short*)(ws + OFF_X);
  unsigned short* ybuf   = (unsigned short*)(ws + OFF_X);
  float*          qa     = ws + OFF_QA;
  float*          qbuf   = ws + OFF_QA;
  unsigned short* gate_bf= (unsigned short*)(ws + OFF_GATE);
  unsigned short* down_bf= (unsigned short*)(ws + OFF_GATE);
  unsigned short* up_bf  = (unsigned short*)(ws + OFF_UP);
  unsigned short* qab    = (unsigned short*)(ws + OFF_QAB);
  float*          kvp    = ws + OFF_KVP;
  unsigned short* kvc    = (unsigned short*)(ws + OFF_KVC);
  unsigned short* actb   = (unsigned short*)(ws + OFF_ACT);
  unsigned short* wqa_bf = (unsigned short*)(ws + OFF_WA + WA_WQA);
  unsigned short* wqb_bf = (unsigned short*)(ws + OFF_WA + WA_WQB);
  unsigned short* wkva_bf= (unsigned short*)(ws + OFF_WA + WA_WKVA);
  unsigned short* wo_bf  = (unsigned short*)(ws + OFF_WA + WA_WO);

  float* out    = (float*)d_out;
  float* logits = out + (size_t)NTOK * ND;

  // ---- merged early weight conversions (4 conv + gwp in one launch)
  conv_weights_kernel<<<1328, 256, 0, stream>>>(
      wq_a_w, wkv_a_w, wq_b_w, wo_w, gate_w, post_ln_w,
      wqa_bf, wkva_bf, wqb_bf, wo_bf, gwp);

  // ---- forward
  rmsnorm_bf16<4><<<NTOK, 256, 0, stream>>>(hidden, ND, in_ln_w, x_bf, ND);
  gemm_bf16<false,false><<<dim3(4, 32), 256, 0, stream>>>(
      x_bf, ND, wqa_bf, ND, wq_a_b, nullptr, qa, 512, 512, ND);
  gemm_bf16<false,false><<<dim3(3, 32), 256, 0, stream>>>(
      x_bf, ND, wkva_bf, ND, wkv_a_b, nullptr, kvp, 288, 288, ND);
  rmsnorm_bf16<2><<<NTOK, 256, 0, stream>>>(qa, 512, q_norm_w, qab, 512);
  // fused kv rmsnorm + rope_k (bit-identical to the two separate kernels)
  rmsnorm_rope_kv<<<NTOK, 256, 0, stream>>>(kvp, kv_norm_w, kvc);
  // qbuf GEMM with fused rope_q epilogue (bit-identical to gemm + separate rope_q)
  gemm_bf16<false,false,true><<<dim3(12, 32), 256, 0, stream>>>(
      qab, 512, wqb_bf, 512, wq_b_b, nullptr, qbuf, 1536, 1536, 512);
  {
    size_t smem = 54528;
    hipFuncSetAttribute((const void*)attn_kernel,
                        hipFuncAttributeMaxDynamicSharedMemorySize, (int)smem);
    attn_kernel<<<dim3(8, NH, NB), 256, smem, stream>>>(qbuf, kvc, wkv_b_w, oproj);
  }
  // qbuf/QAB/KVP/KVC regions dead -> MoE weight conversions (gate+up merged)
  conv_gu_kernel<<<8192, 256, 0, stream>>>(gate_proj, up_proj, gate_bf, up_bf);
  // h = oproj @ wo^T + wo_b + hidden -> d_out (f32)
  gemm_bf16<false,true><<<dim3(8, 32), 256, 0, stream>>>(
      oproj, ND, wo_bf, ND, wo_b, hidden, out, ND, ND, ND);
  // fused post-LN rmsnorm (ybuf) + gate logits
  rms_gate_kernel<<<NTOK, 256, 0, stream>>>(out, post_ln_w, gwp, gate_b, ybuf, logits);
  hipMemsetAsync(cnt, 0, 32 * sizeof(int), stream);
  hipMemsetAsync(etok, 0xFF, ETOK_CAP * sizeof(int), stream);
  topk_kernel<<<16, 256, 0, stream>>>(logits, tke, tkw, cnt);
  offsets_kernel<<<1, 64, 0, stream>>>(cnt, base, pcnt);
  scatter_kernel<<<16, 256, 0, stream>>>(tke, tkw, base, cnt2, etok, ew);
  moe_mlp1_mfma<<<dim3(16, 32, 16), 256, 0, stream>>>(ybuf, gate_bf, up_bf,
                                                      etok, base, pcnt, actb);
  // gate_bf dead -> down_bf conversion
  conv_bf16_kernel<<<4096, 256, 0, stream>>>(down_proj, down_bf, 8388608);
  moe_down_mfma<<<dim3(8, 32, 8), 256, 0, stream>>>(actb, down_bf, etok, ew,
                                                    base, pcnt, 0, out);
  moe_down_mfma<<<dim3(8, 32, 8), 256, 0, stream>>>(actb, down_bf, etok, ew,
                                                    base, pcnt, 1, out);
}